// Round 9
// baseline (4070.909 us; speedup 1.0000x reference)
//
#include <hip/hip_runtime.h>
#include <math.h>

#define NN 8000   // nodes
#define CD 64     // node feature dim / C_OUT
#define DG 16     // neighbors per node
#define HD 128    // GRU hidden
#define G3 384    // 3*HD
#define TT 4      // walk steps
// Worst-case f32 noisy-score error bound ~1e-3; MARGIN = 4e-3 (proven in r8).
// Trips (~25% of nodes) are handled by the cheap block-parallel f64 fix.
#define MARGIN 4e-3f

#if __has_builtin(__builtin_amdgcn_rcpf)
#define RCP(x) __builtin_amdgcn_rcpf(x)
#else
#define RCP(x) (1.f/(x))
#endif

// fast f32 (walk + wgru; error ~1e-6 << MARGIN)
__device__ __forceinline__ float fsig (float x){ return RCP(1.f + __expf(-x)); }
__device__ __forceinline__ float ftanh(float x){ return 1.f - 2.f*RCP(1.f + __expf(2.f*x)); }

// fast f64 exp: range-reduced 13-term Horner, ~3 ulp. Decisions vs np-f64
// would need a noisy-score gap < ~1e-13 to flip — negligible.
__device__ __forceinline__ double fexp64(double x){
    const double LOG2E  = 1.4426950408889634074;
    const double LN2_HI = 6.93147180369123816490e-01;
    const double LN2_LO = 1.90821492927058770002e-10;
    x = fmin(fmax(x, -700.0), 700.0);
    double fn = rint(x * LOG2E);
    double r  = fma(-fn, LN2_HI, x);
    r = fma(-fn, LN2_LO, r);
    double p = 1.6059043836821613e-10;            // 1/13!
    p = fma(p, r, 2.0876756987868099e-09);        // 1/12!
    p = fma(p, r, 2.5052108385441719e-08);        // 1/11!
    p = fma(p, r, 2.7557319223985893e-07);        // 1/10!
    p = fma(p, r, 2.7557319223985888e-06);        // 1/9!
    p = fma(p, r, 2.4801587301587302e-05);        // 1/8!
    p = fma(p, r, 1.9841269841269841e-04);        // 1/7!
    p = fma(p, r, 1.3888888888888889e-03);        // 1/6!
    p = fma(p, r, 8.3333333333333332e-03);        // 1/5!
    p = fma(p, r, 4.1666666666666664e-02);        // 1/4!
    p = fma(p, r, 1.6666666666666666e-01);        // 1/3!
    p = fma(p, r, 0.5);
    p = fma(p, r, 1.0);
    p = fma(p, r, 1.0);
    long long bits = __double_as_longlong(p) + ((long long)(int)fn << 52);
    return __longlong_as_double(bits);
}
__device__ __forceinline__ double sig64f (double x){ return 1.0/(1.0 + fexp64(-x)); }
__device__ __forceinline__ double tanh64f(double x){ return 1.0 - 2.0/(fexp64(2.0*x) + 1.0); }

// XG precompute in f64; emit packed-hi [n][64][8] (+ optional residual [n][64][6]).
// Slot q of lane l holds XG[n][64*q + l]; matches hg[m] register order.
__global__ __launch_bounds__(384) void xg_kernel(const float* __restrict__ A,
    const float* __restrict__ W, const float* __restrict__ b,
    float* __restrict__ hiP, float* __restrict__ loP)
{
    __shared__ float a_s[8][64];
    const int g  = threadIdx.x;        // 0..383
    const int l  = g & 63, q = g >> 6;
    const int n0 = blockIdx.x * 8;
    for (int idx = threadIdx.x; idx < 8*64; idx += 384)
        a_s[idx>>6][idx&63] = A[(size_t)n0*64 + idx];
    __syncthreads();
    double acc[8];
    const double bg = (double)b[g];
#pragma unroll
    for (int j=0;j<8;j++) acc[j] = bg;
    for (int c=0;c<64;c++){
        const double w = (double)W[c*G3 + g];
#pragma unroll
        for (int j=0;j<8;j++) acc[j] += (double)a_s[j][c]*w;
    }
#pragma unroll
    for (int j=0;j<8;j++){
        const size_t base = (size_t)(n0+j)*64 + l;
        const float hi = (float)acc[j];
        hiP[base*8 + q] = hi;
        if (q < 2) hiP[base*8 + 6 + q] = 0.f;       // zero pad slots
        if (loP) loP[base*6 + q] = (float)(acc[j] - (double)hi);
    }
}

// Repack Wh [k][384] -> [k][lane][8] (slot m = W[k][64*m+lane], slots 6,7 = 0).
__global__ __launch_bounds__(256) void repack_kernel(const float* __restrict__ W,
                                                     float* __restrict__ P)
{
    const int idx = blockIdx.x*256 + threadIdx.x;   // 0 .. 128*512-1
    const int k = idx >> 9, rem = idx & 511, l = rem >> 3, s = rem & 7;
    P[idx] = (s < 6) ? W[k*G3 + s*64 + l] : 0.f;
}

// Phase 1: pure-f32 walk, one wave per node, no barriers, fast transcendentals.
// Margin failures are appended to fail_list for the f64 fixup kernel.
__global__ __launch_bounds__(256) void walk_kernel(
    const int*   __restrict__ nbrs,  const float* __restrict__ noise,
    const float* __restrict__ XGfP,  const float* __restrict__ dWhP,
    const float* __restrict__ dbh,   const float* __restrict__ dWo,
    const float* __restrict__ dbo,
    int* __restrict__ paths, int* __restrict__ fail_cnt, int* __restrict__ fail_list,
    float* __restrict__ out)
{
    __shared__ float hf_s[4][HD];

    const int wid  = threadIdx.x >> 6;
    const int lane = threadIdx.x & 63;
    const int node = blockIdx.x*4 + wid;

    float h0 = 0.f, h1 = 0.f;
    float dbhf[6], hgf[6];
#pragma unroll
    for (int m=0;m<6;m++){ dbhf[m] = dbh[lane+64*m]; hgf[m] = dbhf[m]; }
    const float wo0f0 = dWo[lane*CD];          // dWo[:,0] lane-local
    const float wo0f1 = dWo[(lane+64)*CD];
    const float dbo0f = dbo[0];

    int  cur = node;
    int  ch0=0, ch1=0, ch2=0, ch3=0;
    bool pushed = false;

    for (int t=0;t<TT;t++){
        if      (t==0) ch0 = cur;
        else if (t==1) ch1 = cur;
        else if (t==2) ch2 = cur;
        else           ch3 = cur;

        // ---- extend prefix (packed row: 2 x b128) ----
        {
            const float4* xr = (const float4*)(XGfP + ((size_t)cur*64 + lane)*8);
            const float4 A = xr[0], B = xr[1];
            float r = fsig (A.x + hgf[0]);
            float z = fsig (A.z + hgf[2]);
            float n = ftanh(B.x + r*hgf[4]);
            h0 = (1.f-z)*n + z*h0;
            r = fsig (A.y + hgf[1]);
            z = fsig (A.w + hgf[3]);
            n = ftanh(B.y + r*hgf[5]);
            h1 = (1.f-z)*n + z*h1;
        }
        hf_s[wid][lane] = h0;  hf_s[wid][lane+64] = h1;

        // ---- matvec: hgf = dbh + h@dWh (packed: per k, float4 stride = 128) ----
        {
            float acc[6];
#pragma unroll
            for (int m=0;m<6;m++) acc[m] = dbhf[m];
            const float4* wr = (const float4*)(dWhP + (size_t)lane*8);
#pragma unroll 4
            for (int k=0;k<HD;k++){
                const float hk = hf_s[wid][k];
                const float4 W0 = wr[k*128], W1 = wr[k*128+1];
                acc[0] += hk*W0.x; acc[1] += hk*W0.y; acc[2] += hk*W0.z;
                acc[3] += hk*W0.w; acc[4] += hk*W1.x; acc[5] += hk*W1.y;
            }
#pragma unroll
            for (int m=0;m<6;m++) hgf[m] = acc[m];
        }

        // ---- 16 candidates, 4 groups of 4 with prefetch ----
        int   nbrv = (lane < DG) ? nbrs[(size_t)cur*DG + lane] : 0;
        float nz   = (lane < DG) ? noise[((size_t)t*NN + node)*DG + lane] : 0.f;
        float lf = -3.0e38f;
#pragma unroll
        for (int g=0; g<4; g++){
            float4 CA[4], CB[4];
#pragma unroll
            for (int j=0;j<4;j++){
                const int nd = __shfl(nbrv, g*4+j);
                const float4* cr = (const float4*)(XGfP + ((size_t)nd*64 + lane)*8);
                CA[j] = cr[0];  CB[j] = cr[1];
            }
            float part[4];
#pragma unroll
            for (int j=0;j<4;j++){
                float r = fsig (CA[j].x + hgf[0]);
                float z = fsig (CA[j].z + hgf[2]);
                float n = ftanh(CB[j].x + r*hgf[4]);
                part[j]  = ((1.f-z)*n + z*h0) * wo0f0;
                r = fsig (CA[j].y + hgf[1]);
                z = fsig (CA[j].w + hgf[3]);
                n = ftanh(CB[j].y + r*hgf[5]);
                part[j] += ((1.f-z)*n + z*h1) * wo0f1;
            }
#pragma unroll
            for (int off=32; off>0; off>>=1){
#pragma unroll
                for (int j=0;j<4;j++) part[j] += __shfl_xor(part[j], off);
            }
#pragma unroll
            for (int j=0;j<4;j++) if (lane == g*4+j) lf = part[j] + dbo0f;
        }

        // ---- softmax + noisy argmax + top-2 margin ----
        float v  = (lane < DG) ? lf : -3.0e38f;
        float mx = v;
#pragma unroll
        for (int off=32; off>0; off>>=1) mx = fmaxf(mx, __shfl_xor(mx, off));
        float e = (lane < DG) ? __expf(v - mx) : 0.f;
        float s = e;
#pragma unroll
        for (int off=32; off>0; off>>=1) s += __shfl_xor(s, off);
        const float normf = mx + __logf(s);

        float noisyf = (lane < DG) ? __expf(v - normf) + 0.01f*nz : -3.0e38f;
        int   idx = lane;
        float bv  = noisyf;
#pragma unroll
        for (int off=32; off>0; off>>=1){
            float ov = __shfl_xor(bv, off);
            int   oi = __shfl_xor(idx, off);
            if (ov > bv || (ov == bv && oi < idx)){ bv = ov; idx = oi; }
        }
        float sv = (lane == idx || lane >= DG) ? -3.0e38f : noisyf;
#pragma unroll
        for (int off=32; off>0; off>>=1) sv = fmaxf(sv, __shfl_xor(sv, off));

        const bool trip = (bv - sv) < MARGIN;   // wave-uniform
        if (trip && !pushed && lane == 0){
            const int slot = atomicAdd(fail_cnt, 1);
            if (slot < NN) fail_list[slot] = node;
        }
        pushed = pushed || trip;

        const float lpf = __shfl(v, idx) - normf;
        if (lane == 0) out[NN*CD + node*TT + t] = lpf;
        cur = __shfl(nbrv, idx);
    }

    if (lane == 0){
        int* p = paths + (size_t)node*8;
        p[0]=ch0; p[1]=ch1; p[2]=ch2; p[3]=ch3; p[4]=cur;
    }
}

// Phase 2: exact-f64 full-walk redo, ONE NODE PER BLOCK (4 waves).
// Candidates split 4-per-wave via LDS logits; hidden shared via LDS; all
// waves redo softmax/argmax redundantly (identical fexp64 arithmetic).
__global__ __launch_bounds__(256) void fix_kernel(
    const int*   __restrict__ nbrs,  const float* __restrict__ noise,
    const float* __restrict__ XGfP,  const float* __restrict__ XGrP,
    const float* __restrict__ dWh,   const float* __restrict__ dbh,
    const float* __restrict__ dWo,   const float* __restrict__ dbo,
    const int* __restrict__ fail_cnt, const int* __restrict__ fail_list,
    int* __restrict__ paths, float* __restrict__ out)
{
    __shared__ double h_s[HD];
    __shared__ double sc_s[DG];
    const int wid  = threadIdx.x >> 6;
    const int lane = threadIdx.x & 63;
    const int count = min(fail_cnt[0], NN);

    double db64[6];
#pragma unroll
    for (int m=0;m<6;m++) db64[m] = (double)dbh[lane+64*m];
    const double wo0d0 = (double)dWo[lane*CD];
    const double wo0d1 = (double)dWo[(lane+64)*CD];
    const double dbo0d = (double)dbo[0];

    for (int ii = blockIdx.x; ii < count; ii += gridDim.x){
        const int node = fail_list[ii];
        double H0 = 0.0, H1 = 0.0;
        double g64[6];
#pragma unroll
        for (int m=0;m<6;m++) g64[m] = db64[m];
        int cur = node;
        int c0=0,c1=0,c2=0,c3=0;

        for (int t=0;t<TT;t++){
            if      (t==0) c0 = cur;
            else if (t==1) c1 = cur;
            else if (t==2) c2 = cur;
            else           c3 = cur;

            // ---- extend (f64 = hi + residual); identical in all 4 waves ----
            {
                const size_t base = (size_t)cur*64 + lane;
                const float* hi = XGfP + base*8;
                const float* lo = XGrP + base*6;
                double r = sig64f (((double)hi[0]+(double)lo[0]) + g64[0]);
                double z = sig64f (((double)hi[2]+(double)lo[2]) + g64[2]);
                double n = tanh64f(((double)hi[4]+(double)lo[4]) + r*g64[4]);
                H0 = (1.0-z)*n + z*H0;
                r = sig64f (((double)hi[1]+(double)lo[1]) + g64[1]);
                z = sig64f (((double)hi[3]+(double)lo[3]) + g64[3]);
                n = tanh64f(((double)hi[5]+(double)lo[5]) + r*g64[5]);
                H1 = (1.0-z)*n + z*H1;
            }
            if (wid == 0){ h_s[lane] = H0; h_s[lane+64] = H1; }
            __syncthreads();   // (A) h ready for matvec

            // ---- matvec f64 (redundant per wave; fma-only) ----
#pragma unroll
            for (int m=0;m<6;m++) g64[m] = db64[m];
            {
                const float* wp = dWh + lane;
                for (int k=0;k<HD;k++){
                    const double hk = h_s[k];
#pragma unroll
                    for (int m=0;m<6;m++)
                        g64[m] += hk * (double)wp[(size_t)k*G3 + 64*m];
                }
            }

            // ---- candidates: wave wid scores d = wid*4 .. wid*4+3 ----
            int   nbrv = (lane < DG) ? nbrs[(size_t)cur*DG + lane] : 0;
            float nz   = (lane < DG) ? noise[((size_t)t*NN + node)*DG + lane] : 0.f;
#pragma unroll
            for (int j=0;j<4;j++){
                const int d  = wid*4 + j;
                const int nd = __shfl(nbrv, d);
                const size_t base = (size_t)nd*64 + lane;
                const float* hi = XGfP + base*8;
                const float* lo = XGrP + base*6;
                double r = sig64f (((double)hi[0]+(double)lo[0]) + g64[0]);
                double z = sig64f (((double)hi[2]+(double)lo[2]) + g64[2]);
                double n = tanh64f(((double)hi[4]+(double)lo[4]) + r*g64[4]);
                double part = ((1.0-z)*n + z*H0) * wo0d0;
                r = sig64f (((double)hi[1]+(double)lo[1]) + g64[1]);
                z = sig64f (((double)hi[3]+(double)lo[3]) + g64[3]);
                n = tanh64f(((double)hi[5]+(double)lo[5]) + r*g64[5]);
                part += ((1.0-z)*n + z*H1) * wo0d1;
#pragma unroll
                for (int off=32; off>0; off>>=1) part += __shfl_xor(part, off);
                if (lane == 0) sc_s[d] = part + dbo0d;
            }
            __syncthreads();   // (B) all 16 logits ready

            // ---- softmax + noisy argmax (redundant, identical in all waves) ----
            double dv = (lane < DG) ? sc_s[lane] : -1e300;
            double dmx = dv;
#pragma unroll
            for (int off=32; off>0; off>>=1) dmx = fmax(dmx, __shfl_xor(dmx, off));
            double de = (lane < DG) ? fexp64(dv - dmx) : 0.0;
            double ds = de;
#pragma unroll
            for (int off=32; off>0; off>>=1) ds += __shfl_xor(ds, off);
            const double dnorm = dmx + log(ds);
            double dnoisy = (lane < DG) ? fexp64(dv - dnorm) + 0.01*(double)nz : -1e300;
            int di = lane;
#pragma unroll
            for (int off=32; off>0; off>>=1){
                double ov = __shfl_xor(dnoisy, off);
                int    oi = __shfl_xor(di, off);
                if (ov > dnoisy || (ov == dnoisy && oi < di)){ dnoisy = ov; di = oi; }
            }
            const double lpfix = __shfl(dv, di) - dnorm;
            if (wid == 0 && lane == 0) out[NN*CD + node*TT + t] = (float)lpfix;
            cur = __shfl(nbrv, di);
        }
        if (wid == 0 && lane == 0){
            int* p = paths + (size_t)node*8;
            p[0]=c0; p[1]=c1; p[2]=c2; p[3]=c3; p[4]=cur;
        }
    }
}

// w-GRU over the recorded 5-node walk (packed loads, fast transcendentals).
__global__ __launch_bounds__(256) void wgru_kernel(
    const int*   __restrict__ paths, const float* __restrict__ XGwP,
    const float* __restrict__ wWhP,  const float* __restrict__ wbh,
    const float* __restrict__ wWo,   const float* __restrict__ wbo,
    float* __restrict__ out)
{
    __shared__ float hw_s[4][HD];
    const int wid  = threadIdx.x >> 6;
    const int lane = threadIdx.x & 63;
    const int node = blockIdx.x*4 + wid;

    float h0 = 0.f, h1 = 0.f;
    float wb[6], hg[6];
#pragma unroll
    for (int m=0;m<6;m++){ wb[m] = wbh[lane+64*m]; hg[m] = wb[m]; }
    const int* p = paths + (size_t)node*8;

#pragma unroll
    for (int s=0; s<=TT; s++){
        const int c = p[s];
        const float4* xr = (const float4*)(XGwP + ((size_t)c*64 + lane)*8);
        const float4 A = xr[0], B = xr[1];
        float r = fsig (A.x + hg[0]);
        float z = fsig (A.z + hg[2]);
        float n = ftanh(B.x + r*hg[4]);
        h0 = (1.f-z)*n + z*h0;
        r = fsig (A.y + hg[1]);
        z = fsig (A.w + hg[3]);
        n = ftanh(B.y + r*hg[5]);
        h1 = (1.f-z)*n + z*h1;
        if (s < TT){
            hw_s[wid][lane] = h0;  hw_s[wid][lane+64] = h1;
            float acc[6];
#pragma unroll
            for (int m=0;m<6;m++) acc[m] = wb[m];
            const float4* wr = (const float4*)(wWhP + (size_t)lane*8);
#pragma unroll 4
            for (int k=0;k<HD;k++){
                const float hk = hw_s[wid][k];
                const float4 W0 = wr[k*128], W1 = wr[k*128+1];
                acc[0] += hk*W0.x; acc[1] += hk*W0.y; acc[2] += hk*W0.z;
                acc[3] += hk*W0.w; acc[4] += hk*W1.x; acc[5] += hk*W1.y;
            }
#pragma unroll
            for (int m=0;m<6;m++) hg[m] = acc[m];
        }
    }
    hw_s[wid][lane] = h0;  hw_s[wid][lane+64] = h1;

    float acc = wbo[lane];                 // CD == 64 == wave width
    const float* wcol = wWo + lane;
    for (int i=0;i<HD;i++) acc += hw_s[wid][i] * wcol[(size_t)i*CD];
    out[(size_t)node*CD + lane] = acc;
}

extern "C" void kernel_launch(void* const* d_in, const int* in_sizes, int n_in,
                              void* d_out, int out_size, void* d_ws, size_t ws_size,
                              hipStream_t stream)
{
    const float* attr  = (const float*)d_in[0];
    const int*   nbrs  = (const int*)  d_in[1];
    const float* noise = (const float*)d_in[2];
    const float* dWx = (const float*)d_in[3];
    const float* dWh = (const float*)d_in[4];
    const float* dbx = (const float*)d_in[5];
    const float* dbh = (const float*)d_in[6];
    const float* dWo = (const float*)d_in[7];
    const float* dbo = (const float*)d_in[8];
    const float* wWx = (const float*)d_in[9];
    const float* wWh = (const float*)d_in[10];
    const float* wbx = (const float*)d_in[11];
    const float* wbh = (const float*)d_in[12];
    const float* wWo = (const float*)d_in[13];
    const float* wbo = (const float*)d_in[14];
    float* out = (float*)d_out;

    char* ws = (char*)d_ws;
    float* XGfP      = (float*)(ws);                 // 8000*64*8*4 = 16,384,000 B
    float* XGrP      = (float*)(ws + 16384000);      // 8000*64*6*4 = 12,288,000 B
    float* XGwP      = (float*)(ws + 28672000);      // 16,384,000 B
    float* dWhP      = (float*)(ws + 45056000);      // 262,144 B
    float* wWhP      = (float*)(ws + 45318144);      // 262,144 B
    int*   paths     = (int*)  (ws + 45580288);      // 256,000 B
    int*   fail_list = (int*)  (ws + 45836288);      // 32,000 B
    int*   fail_cnt  = (int*)  (ws + 45868288);      // 4 B   (total ~45.9 MB)

    hipMemsetAsync(fail_cnt, 0, sizeof(int), stream);

    xg_kernel<<<NN/8, G3, 0, stream>>>(attr, dWx, dbx, XGfP, XGrP);
    xg_kernel<<<NN/8, G3, 0, stream>>>(attr, wWx, wbx, XGwP, nullptr);
    repack_kernel<<<(HD*64*8)/256, 256, 0, stream>>>(dWh, dWhP);
    repack_kernel<<<(HD*64*8)/256, 256, 0, stream>>>(wWh, wWhP);

    walk_kernel<<<NN/4, 256, 0, stream>>>(nbrs, noise, XGfP, dWhP,
                                          dbh, dWo, dbo,
                                          paths, fail_cnt, fail_list, out);
    fix_kernel<<<2000, 256, 0, stream>>>(nbrs, noise, XGfP, XGrP,
                                         dWh, dbh, dWo, dbo,
                                         fail_cnt, fail_list, paths, out);
    wgru_kernel<<<NN/4, 256, 0, stream>>>(paths, XGwP, wWhP, wbh, wWo, wbo, out);
}

// Round 10
// 948.527 us; speedup vs baseline: 4.2918x; 4.2918x over previous
//
#include <hip/hip_runtime.h>
#include <math.h>

#define NN 8000   // nodes
#define CD 64     // node feature dim / C_OUT
#define DG 16     // neighbors per node
#define HD 128    // GRU hidden
#define G3 384    // 3*HD
#define TT 4      // walk steps
// Worst-case f32 noisy-score error bound ~1e-3; MARGIN = 4e-3 (proven r8/r9).
#define MARGIN 4e-3f

#if __has_builtin(__builtin_amdgcn_rcpf)
#define RCP(x) __builtin_amdgcn_rcpf(x)
#else
#define RCP(x) (1.f/(x))
#endif

// fast f32 (walk + wgru; error ~1e-6 << MARGIN)
__device__ __forceinline__ float fsig (float x){ return RCP(1.f + __expf(-x)); }
__device__ __forceinline__ float ftanh(float x){ return 1.f - 2.f*RCP(1.f + __expf(2.f*x)); }

// fast f64 exp: range-reduced 13-term Horner, ~3 ulp (validated r9).
__device__ __forceinline__ double fexp64(double x){
    const double LOG2E  = 1.4426950408889634074;
    const double LN2_HI = 6.93147180369123816490e-01;
    const double LN2_LO = 1.90821492927058770002e-10;
    x = fmin(fmax(x, -700.0), 700.0);
    double fn = rint(x * LOG2E);
    double r  = fma(-fn, LN2_HI, x);
    r = fma(-fn, LN2_LO, r);
    double p = 1.6059043836821613e-10;            // 1/13!
    p = fma(p, r, 2.0876756987868099e-09);
    p = fma(p, r, 2.5052108385441719e-08);
    p = fma(p, r, 2.7557319223985893e-07);
    p = fma(p, r, 2.7557319223985888e-06);
    p = fma(p, r, 2.4801587301587302e-05);
    p = fma(p, r, 1.9841269841269841e-04);
    p = fma(p, r, 1.3888888888888889e-03);
    p = fma(p, r, 8.3333333333333332e-03);
    p = fma(p, r, 4.1666666666666664e-02);
    p = fma(p, r, 1.6666666666666666e-01);
    p = fma(p, r, 0.5);
    p = fma(p, r, 1.0);
    p = fma(p, r, 1.0);
    long long bits = __double_as_longlong(p) + ((long long)(int)fn << 52);
    return __longlong_as_double(bits);
}
__device__ __forceinline__ double sig64f (double x){ return 1.0/(1.0 + fexp64(-x)); }
__device__ __forceinline__ double tanh64f(double x){ return 1.0 - 2.0/(fexp64(2.0*x) + 1.0); }

// XG precompute in f64; emit packed-hi [n][64][8] (+ optional residual [n][64][6]).
// Slot q of lane l holds XG[n][64*q + l]; matches hg[m] register order.
__global__ __launch_bounds__(384) void xg_kernel(const float* __restrict__ A,
    const float* __restrict__ W, const float* __restrict__ b,
    float* __restrict__ hiP, float* __restrict__ loP)
{
    __shared__ float a_s[8][64];
    const int g  = threadIdx.x;        // 0..383
    const int l  = g & 63, q = g >> 6;
    const int n0 = blockIdx.x * 8;
    for (int idx = threadIdx.x; idx < 8*64; idx += 384)
        a_s[idx>>6][idx&63] = A[(size_t)n0*64 + idx];
    __syncthreads();
    double acc[8];
    const double bg = (double)b[g];
#pragma unroll
    for (int j=0;j<8;j++) acc[j] = bg;
    for (int c=0;c<64;c++){
        const double w = (double)W[c*G3 + g];
#pragma unroll
        for (int j=0;j<8;j++) acc[j] += (double)a_s[j][c]*w;
    }
#pragma unroll
    for (int j=0;j<8;j++){
        const size_t base = (size_t)(n0+j)*64 + l;
        const float hi = (float)acc[j];
        hiP[base*8 + q] = hi;
        if (q < 2) hiP[base*8 + 6 + q] = 0.f;       // zero pad slots
        if (loP) loP[base*6 + q] = (float)(acc[j] - (double)hi);
    }
}

// Repack Wh [k][384] -> [k][lane][8] (slot m = W[k][64*m+lane], slots 6,7 = 0).
__global__ __launch_bounds__(256) void repack_kernel(const float* __restrict__ W,
                                                     float* __restrict__ P)
{
    const int idx = blockIdx.x*256 + threadIdx.x;   // 0 .. 128*512-1
    const int k = idx >> 9, rem = idx & 511, l = rem >> 3, s = rem & 7;
    P[idx] = (s < 6) ? W[k*G3 + s*64 + l] : 0.f;
}

// Phase 1: pure-f32 walk, one wave per node, no barriers, fast transcendentals.
// Margin failures are appended to fail_list for the f64 fixup kernel.
__global__ __launch_bounds__(256) void walk_kernel(
    const int*   __restrict__ nbrs,  const float* __restrict__ noise,
    const float* __restrict__ XGfP,  const float* __restrict__ dWhP,
    const float* __restrict__ dbh,   const float* __restrict__ dWo,
    const float* __restrict__ dbo,
    int* __restrict__ paths, int* __restrict__ fail_cnt, int* __restrict__ fail_list,
    float* __restrict__ out)
{
    __shared__ float hf_s[4][HD];

    const int wid  = threadIdx.x >> 6;
    const int lane = threadIdx.x & 63;
    const int node = blockIdx.x*4 + wid;

    float h0 = 0.f, h1 = 0.f;
    float dbhf[6], hgf[6];
#pragma unroll
    for (int m=0;m<6;m++){ dbhf[m] = dbh[lane+64*m]; hgf[m] = dbhf[m]; }
    const float wo0f0 = dWo[lane*CD];          // dWo[:,0] lane-local
    const float wo0f1 = dWo[(lane+64)*CD];
    const float dbo0f = dbo[0];

    int  cur = node;
    int  ch0=0, ch1=0, ch2=0, ch3=0;
    bool pushed = false;

    for (int t=0;t<TT;t++){
        if      (t==0) ch0 = cur;
        else if (t==1) ch1 = cur;
        else if (t==2) ch2 = cur;
        else           ch3 = cur;

        // ---- extend prefix (packed row: 2 x b128) ----
        {
            const float4* xr = (const float4*)(XGfP + ((size_t)cur*64 + lane)*8);
            const float4 A = xr[0], B = xr[1];
            float r = fsig (A.x + hgf[0]);
            float z = fsig (A.z + hgf[2]);
            float n = ftanh(B.x + r*hgf[4]);
            h0 = (1.f-z)*n + z*h0;
            r = fsig (A.y + hgf[1]);
            z = fsig (A.w + hgf[3]);
            n = ftanh(B.y + r*hgf[5]);
            h1 = (1.f-z)*n + z*h1;
        }
        hf_s[wid][lane] = h0;  hf_s[wid][lane+64] = h1;

        // ---- matvec: hgf = dbh + h@dWh (packed: per k, float4 stride = 128) ----
        {
            float acc[6];
#pragma unroll
            for (int m=0;m<6;m++) acc[m] = dbhf[m];
            const float4* wr = (const float4*)(dWhP + (size_t)lane*8);
#pragma unroll 4
            for (int k=0;k<HD;k++){
                const float hk = hf_s[wid][k];
                const float4 W0 = wr[k*128], W1 = wr[k*128+1];
                acc[0] += hk*W0.x; acc[1] += hk*W0.y; acc[2] += hk*W0.z;
                acc[3] += hk*W0.w; acc[4] += hk*W1.x; acc[5] += hk*W1.y;
            }
#pragma unroll
            for (int m=0;m<6;m++) hgf[m] = acc[m];
        }

        // ---- 16 candidates, 4 groups of 4 with prefetch ----
        int   nbrv = (lane < DG) ? nbrs[(size_t)cur*DG + lane] : 0;
        float nz   = (lane < DG) ? noise[((size_t)t*NN + node)*DG + lane] : 0.f;
        float lf = -3.0e38f;
#pragma unroll
        for (int g=0; g<4; g++){
            float4 CA[4], CB[4];
#pragma unroll
            for (int j=0;j<4;j++){
                const int nd = __shfl(nbrv, g*4+j);
                const float4* cr = (const float4*)(XGfP + ((size_t)nd*64 + lane)*8);
                CA[j] = cr[0];  CB[j] = cr[1];
            }
            float part[4];
#pragma unroll
            for (int j=0;j<4;j++){
                float r = fsig (CA[j].x + hgf[0]);
                float z = fsig (CA[j].z + hgf[2]);
                float n = ftanh(CB[j].x + r*hgf[4]);
                part[j]  = ((1.f-z)*n + z*h0) * wo0f0;
                r = fsig (CA[j].y + hgf[1]);
                z = fsig (CA[j].w + hgf[3]);
                n = ftanh(CB[j].y + r*hgf[5]);
                part[j] += ((1.f-z)*n + z*h1) * wo0f1;
            }
#pragma unroll
            for (int off=32; off>0; off>>=1){
#pragma unroll
                for (int j=0;j<4;j++) part[j] += __shfl_xor(part[j], off);
            }
#pragma unroll
            for (int j=0;j<4;j++) if (lane == g*4+j) lf = part[j] + dbo0f;
        }

        // ---- softmax + noisy argmax + top-2 margin ----
        float v  = (lane < DG) ? lf : -3.0e38f;
        float mx = v;
#pragma unroll
        for (int off=32; off>0; off>>=1) mx = fmaxf(mx, __shfl_xor(mx, off));
        float e = (lane < DG) ? __expf(v - mx) : 0.f;
        float s = e;
#pragma unroll
        for (int off=32; off>0; off>>=1) s += __shfl_xor(s, off);
        const float normf = mx + __logf(s);

        float noisyf = (lane < DG) ? __expf(v - normf) + 0.01f*nz : -3.0e38f;
        int   idx = lane;
        float bv  = noisyf;
#pragma unroll
        for (int off=32; off>0; off>>=1){
            float ov = __shfl_xor(bv, off);
            int   oi = __shfl_xor(idx, off);
            if (ov > bv || (ov == bv && oi < idx)){ bv = ov; idx = oi; }
        }
        float sv = (lane == idx || lane >= DG) ? -3.0e38f : noisyf;
#pragma unroll
        for (int off=32; off>0; off>>=1) sv = fmaxf(sv, __shfl_xor(sv, off));

        const bool trip = (bv - sv) < MARGIN;   // wave-uniform
        if (trip && !pushed && lane == 0){
            const int slot = atomicAdd(fail_cnt, 1);
            if (slot < NN) fail_list[slot] = node;
        }
        pushed = pushed || trip;

        const float lpf = __shfl(v, idx) - normf;
        if (lane == 0) out[NN*CD + node*TT + t] = lpf;
        cur = __shfl(nbrv, idx);
    }

    if (lane == 0){
        int* p = paths + (size_t)node*8;
        p[0]=ch0; p[1]=ch1; p[2]=ch2; p[3]=ch3; p[4]=cur;
    }
}

// Phase 2: exact-f64 full-walk redo, WAVE PER NODE, no barriers (r8 structure
// — max memory-level parallelism; r9's block-per-node + barriers collapsed MLP
// and was 6x slower). Fast-f64 arithmetic identical to r9 (validated).
// Matvec uses packed dWhP (f32->f64 exact), same k-ascending add order as r9.
__global__ __launch_bounds__(256) void fix_kernel(
    const int*   __restrict__ nbrs,  const float* __restrict__ noise,
    const float* __restrict__ XGfP,  const float* __restrict__ XGrP,
    const float* __restrict__ dWhP,  const float* __restrict__ dbh,
    const float* __restrict__ dWo,   const float* __restrict__ dbo,
    const int* __restrict__ fail_cnt, const int* __restrict__ fail_list,
    int* __restrict__ paths, float* __restrict__ out)
{
    __shared__ double h_s[4][HD];
    const int wid  = threadIdx.x >> 6;
    const int lane = threadIdx.x & 63;
    const int nw   = gridDim.x * 4;
    const int count = min(fail_cnt[0], NN);

    double db64[6];
#pragma unroll
    for (int m=0;m<6;m++) db64[m] = (double)dbh[lane+64*m];
    const double wo0d0 = (double)dWo[lane*CD];
    const double wo0d1 = (double)dWo[(lane+64)*CD];
    const double dbo0d = (double)dbo[0];

    for (int ii = blockIdx.x*4 + wid; ii < count; ii += nw){
        const int node = fail_list[ii];
        double H0 = 0.0, H1 = 0.0;
        double g64[6];
#pragma unroll
        for (int m=0;m<6;m++) g64[m] = db64[m];
        int cur = node;
        int c0=0,c1=0,c2=0,c3=0;

        for (int t=0;t<TT;t++){
            if      (t==0) c0 = cur;
            else if (t==1) c1 = cur;
            else if (t==2) c2 = cur;
            else           c3 = cur;

            // ---- extend (f64 = hi + residual) ----
            {
                const size_t base = (size_t)cur*64 + lane;
                const float* hi = XGfP + base*8;
                const float* lo = XGrP + base*6;
                double r = sig64f (((double)hi[0]+(double)lo[0]) + g64[0]);
                double z = sig64f (((double)hi[2]+(double)lo[2]) + g64[2]);
                double n = tanh64f(((double)hi[4]+(double)lo[4]) + r*g64[4]);
                H0 = (1.0-z)*n + z*H0;
                r = sig64f (((double)hi[1]+(double)lo[1]) + g64[1]);
                z = sig64f (((double)hi[3]+(double)lo[3]) + g64[3]);
                n = tanh64f(((double)hi[5]+(double)lo[5]) + r*g64[5]);
                H1 = (1.0-z)*n + z*H1;
            }
            h_s[wid][lane] = H0;  h_s[wid][lane+64] = H1;   // own-wave only

            // ---- matvec f64 (packed weights, 2 x b128 per k; exact cvt) ----
#pragma unroll
            for (int m=0;m<6;m++) g64[m] = db64[m];
            {
                const float4* wr = (const float4*)(dWhP + (size_t)lane*8);
                for (int k=0;k<HD;k++){
                    const double hk = h_s[wid][k];
                    const float4 W0 = wr[k*128], W1 = wr[k*128+1];
                    g64[0] += hk*(double)W0.x; g64[1] += hk*(double)W0.y;
                    g64[2] += hk*(double)W0.z; g64[3] += hk*(double)W0.w;
                    g64[4] += hk*(double)W1.x; g64[5] += hk*(double)W1.y;
                }
            }

            // ---- 16 candidates f64, 4 groups of 4 with prefetch ----
            int   nbrv = (lane < DG) ? nbrs[(size_t)cur*DG + lane] : 0;
            float nz   = (lane < DG) ? noise[((size_t)t*NN + node)*DG + lane] : 0.f;
            double lv = -1e300;
#pragma unroll
            for (int g=0; g<4; g++){
                float ch[4][6], cl[4][6];
#pragma unroll
                for (int j=0;j<4;j++){
                    const int nd = __shfl(nbrv, g*4+j);
                    const size_t base = (size_t)nd*64 + lane;
                    const float* hi = XGfP + base*8;
                    const float* lo = XGrP + base*6;
#pragma unroll
                    for (int q=0;q<6;q++){ ch[j][q]=hi[q]; cl[j][q]=lo[q]; }
                }
#pragma unroll
                for (int j=0;j<4;j++){
                    double r = sig64f (((double)ch[j][0]+(double)cl[j][0]) + g64[0]);
                    double z = sig64f (((double)ch[j][2]+(double)cl[j][2]) + g64[2]);
                    double n = tanh64f(((double)ch[j][4]+(double)cl[j][4]) + r*g64[4]);
                    double part = ((1.0-z)*n + z*H0) * wo0d0;
                    r = sig64f (((double)ch[j][1]+(double)cl[j][1]) + g64[1]);
                    z = sig64f (((double)ch[j][3]+(double)cl[j][3]) + g64[3]);
                    n = tanh64f(((double)ch[j][5]+(double)cl[j][5]) + r*g64[5]);
                    part += ((1.0-z)*n + z*H1) * wo0d1;
#pragma unroll
                    for (int off=32; off>0; off>>=1) part += __shfl_xor(part, off);
                    if (lane == g*4+j) lv = part + dbo0d;
                }
            }

            // ---- softmax + noisy argmax (identical numerics to r9) ----
            double dv = (lane < DG) ? lv : -1e300;
            double dmx = dv;
#pragma unroll
            for (int off=32; off>0; off>>=1) dmx = fmax(dmx, __shfl_xor(dmx, off));
            double de = (lane < DG) ? fexp64(dv - dmx) : 0.0;
            double ds = de;
#pragma unroll
            for (int off=32; off>0; off>>=1) ds += __shfl_xor(ds, off);
            const double dnorm = dmx + log(ds);
            double dnoisy = (lane < DG) ? fexp64(dv - dnorm) + 0.01*(double)nz : -1e300;
            int di = lane;
#pragma unroll
            for (int off=32; off>0; off>>=1){
                double ov = __shfl_xor(dnoisy, off);
                int    oi = __shfl_xor(di, off);
                if (ov > dnoisy || (ov == dnoisy && oi < di)){ dnoisy = ov; di = oi; }
            }
            const double lpfix = __shfl(dv, di) - dnorm;
            if (lane == 0) out[NN*CD + node*TT + t] = (float)lpfix;
            cur = __shfl(nbrv, di);
        }
        if (lane == 0){
            int* p = paths + (size_t)node*8;
            p[0]=c0; p[1]=c1; p[2]=c2; p[3]=c3; p[4]=cur;
        }
    }
}

// w-GRU over the recorded 5-node walk (packed loads, fast transcendentals).
__global__ __launch_bounds__(256) void wgru_kernel(
    const int*   __restrict__ paths, const float* __restrict__ XGwP,
    const float* __restrict__ wWhP,  const float* __restrict__ wbh,
    const float* __restrict__ wWo,   const float* __restrict__ wbo,
    float* __restrict__ out)
{
    __shared__ float hw_s[4][HD];
    const int wid  = threadIdx.x >> 6;
    const int lane = threadIdx.x & 63;
    const int node = blockIdx.x*4 + wid;

    float h0 = 0.f, h1 = 0.f;
    float wb[6], hg[6];
#pragma unroll
    for (int m=0;m<6;m++){ wb[m] = wbh[lane+64*m]; hg[m] = wb[m]; }
    const int* p = paths + (size_t)node*8;

#pragma unroll
    for (int s=0; s<=TT; s++){
        const int c = p[s];
        const float4* xr = (const float4*)(XGwP + ((size_t)c*64 + lane)*8);
        const float4 A = xr[0], B = xr[1];
        float r = fsig (A.x + hg[0]);
        float z = fsig (A.z + hg[2]);
        float n = ftanh(B.x + r*hg[4]);
        h0 = (1.f-z)*n + z*h0;
        r = fsig (A.y + hg[1]);
        z = fsig (A.w + hg[3]);
        n = ftanh(B.y + r*hg[5]);
        h1 = (1.f-z)*n + z*h1;
        if (s < TT){
            hw_s[wid][lane] = h0;  hw_s[wid][lane+64] = h1;
            float acc[6];
#pragma unroll
            for (int m=0;m<6;m++) acc[m] = wb[m];
            const float4* wr = (const float4*)(wWhP + (size_t)lane*8);
#pragma unroll 4
            for (int k=0;k<HD;k++){
                const float hk = hw_s[wid][k];
                const float4 W0 = wr[k*128], W1 = wr[k*128+1];
                acc[0] += hk*W0.x; acc[1] += hk*W0.y; acc[2] += hk*W0.z;
                acc[3] += hk*W0.w; acc[4] += hk*W1.x; acc[5] += hk*W1.y;
            }
#pragma unroll
            for (int m=0;m<6;m++) hg[m] = acc[m];
        }
    }
    hw_s[wid][lane] = h0;  hw_s[wid][lane+64] = h1;

    float acc = wbo[lane];                 // CD == 64 == wave width
    const float* wcol = wWo + lane;
    for (int i=0;i<HD;i++) acc += hw_s[wid][i] * wcol[(size_t)i*CD];
    out[(size_t)node*CD + lane] = acc;
}

extern "C" void kernel_launch(void* const* d_in, const int* in_sizes, int n_in,
                              void* d_out, int out_size, void* d_ws, size_t ws_size,
                              hipStream_t stream)
{
    const float* attr  = (const float*)d_in[0];
    const int*   nbrs  = (const int*)  d_in[1];
    const float* noise = (const float*)d_in[2];
    const float* dWx = (const float*)d_in[3];
    const float* dWh = (const float*)d_in[4];
    const float* dbx = (const float*)d_in[5];
    const float* dbh = (const float*)d_in[6];
    const float* dWo = (const float*)d_in[7];
    const float* dbo = (const float*)d_in[8];
    const float* wWx = (const float*)d_in[9];
    const float* wWh = (const float*)d_in[10];
    const float* wbx = (const float*)d_in[11];
    const float* wbh = (const float*)d_in[12];
    const float* wWo = (const float*)d_in[13];
    const float* wbo = (const float*)d_in[14];
    float* out = (float*)d_out;

    char* ws = (char*)d_ws;
    float* XGfP      = (float*)(ws);                 // 8000*64*8*4 = 16,384,000 B
    float* XGrP      = (float*)(ws + 16384000);      // 8000*64*6*4 = 12,288,000 B
    float* XGwP      = (float*)(ws + 28672000);      // 16,384,000 B
    float* dWhP      = (float*)(ws + 45056000);      // 262,144 B
    float* wWhP      = (float*)(ws + 45318144);      // 262,144 B
    int*   paths     = (int*)  (ws + 45580288);      // 256,000 B
    int*   fail_list = (int*)  (ws + 45836288);      // 32,000 B
    int*   fail_cnt  = (int*)  (ws + 45868288);      // 4 B   (total ~45.9 MB)

    hipMemsetAsync(fail_cnt, 0, sizeof(int), stream);

    xg_kernel<<<NN/8, G3, 0, stream>>>(attr, dWx, dbx, XGfP, XGrP);
    xg_kernel<<<NN/8, G3, 0, stream>>>(attr, wWx, wbx, XGwP, nullptr);
    repack_kernel<<<(HD*64*8)/256, 256, 0, stream>>>(dWh, dWhP);
    repack_kernel<<<(HD*64*8)/256, 256, 0, stream>>>(wWh, wWhP);

    walk_kernel<<<NN/4, 256, 0, stream>>>(nbrs, noise, XGfP, dWhP,
                                          dbh, dWo, dbo,
                                          paths, fail_cnt, fail_list, out);
    fix_kernel<<<2000, 256, 0, stream>>>(nbrs, noise, XGfP, XGrP,
                                         dWhP, dbh, dWo, dbo,
                                         fail_cnt, fail_list, paths, out);
    wgru_kernel<<<NN/4, 256, 0, stream>>>(paths, XGwP, wWhP, wbh, wWo, wbo, out);
}

// Round 11
// 614.627 us; speedup vs baseline: 6.6234x; 1.5433x over previous
//
#include <hip/hip_runtime.h>
#include <math.h>

#define NN 8000   // nodes
#define CD 64     // node feature dim / C_OUT
#define DG 16     // neighbors per node
#define HD 128    // GRU hidden
#define G3 384    // 3*HD
#define TT 4      // walk steps
// Worst-case f32 noisy-score error bound ~1e-3; MARGIN = 4e-3 (proven r8-r10).
#define MARGIN 4e-3f

#if __has_builtin(__builtin_amdgcn_rcpf)
#define RCP(x) __builtin_amdgcn_rcpf(x)
#else
#define RCP(x) (1.f/(x))
#endif

// fast f32 (walk + wgru; error ~1e-6 << MARGIN)
__device__ __forceinline__ float fsig (float x){ return RCP(1.f + __expf(-x)); }
__device__ __forceinline__ float ftanh(float x){ return 1.f - 2.f*RCP(1.f + __expf(2.f*x)); }

// fast f64 exp: range-reduced 13-term Horner, ~3 ulp (validated r9/r10).
__device__ __forceinline__ double fexp64(double x){
    const double LOG2E  = 1.4426950408889634074;
    const double LN2_HI = 6.93147180369123816490e-01;
    const double LN2_LO = 1.90821492927058770002e-10;
    x = fmin(fmax(x, -700.0), 700.0);
    double fn = rint(x * LOG2E);
    double r  = fma(-fn, LN2_HI, x);
    r = fma(-fn, LN2_LO, r);
    double p = 1.6059043836821613e-10;            // 1/13!
    p = fma(p, r, 2.0876756987868099e-09);
    p = fma(p, r, 2.5052108385441719e-08);
    p = fma(p, r, 2.7557319223985893e-07);
    p = fma(p, r, 2.7557319223985888e-06);
    p = fma(p, r, 2.4801587301587302e-05);
    p = fma(p, r, 1.9841269841269841e-04);
    p = fma(p, r, 1.3888888888888889e-03);
    p = fma(p, r, 8.3333333333333332e-03);
    p = fma(p, r, 4.1666666666666664e-02);
    p = fma(p, r, 1.6666666666666666e-01);
    p = fma(p, r, 0.5);
    p = fma(p, r, 1.0);
    p = fma(p, r, 1.0);
    long long bits = __double_as_longlong(p) + ((long long)(int)fn << 52);
    return __longlong_as_double(bits);
}
__device__ __forceinline__ double sig64f (double x){ return 1.0/(1.0 + fexp64(-x)); }
__device__ __forceinline__ double tanh64f(double x){ return 1.0 - 2.0/(fexp64(2.0*x) + 1.0); }

// XG precompute in f64; emit packed-hi [n][64][8] (+ optional residual [n][64][6]).
// Slot q of lane l holds XG[n][64*q + l]; matches hg[m] register order.
__global__ __launch_bounds__(384) void xg_kernel(const float* __restrict__ A,
    const float* __restrict__ W, const float* __restrict__ b,
    float* __restrict__ hiP, float* __restrict__ loP)
{
    __shared__ float a_s[8][64];
    const int g  = threadIdx.x;        // 0..383
    const int l  = g & 63, q = g >> 6;
    const int n0 = blockIdx.x * 8;
    for (int idx = threadIdx.x; idx < 8*64; idx += 384)
        a_s[idx>>6][idx&63] = A[(size_t)n0*64 + idx];
    __syncthreads();
    double acc[8];
    const double bg = (double)b[g];
#pragma unroll
    for (int j=0;j<8;j++) acc[j] = bg;
    for (int c=0;c<64;c++){
        const double w = (double)W[c*G3 + g];
#pragma unroll
        for (int j=0;j<8;j++) acc[j] += (double)a_s[j][c]*w;
    }
#pragma unroll
    for (int j=0;j<8;j++){
        const size_t base = (size_t)(n0+j)*64 + l;
        const float hi = (float)acc[j];
        hiP[base*8 + q] = hi;
        if (q < 2) hiP[base*8 + 6 + q] = 0.f;       // zero pad slots
        if (loP) loP[base*6 + q] = (float)(acc[j] - (double)hi);
    }
}

// Repack Wh [k][384] -> [k][lane][8] (slot m = W[k][64*m+lane], slots 6,7 = 0).
__global__ __launch_bounds__(256) void repack_kernel(const float* __restrict__ W,
                                                     float* __restrict__ P)
{
    const int idx = blockIdx.x*256 + threadIdx.x;   // 0 .. 128*512-1
    const int k = idx >> 9, rem = idx & 511, l = rem >> 3, s = rem & 7;
    P[idx] = (s < 6) ? W[k*G3 + s*64 + l] : 0.f;
}

// Phase 1: pure-f32 walk. 4 waves = 4 nodes per block. The hg matvec is
// BLOCK-COOPERATIVE: wave w covers k in [32w,32w+32) for ALL 4 nodes (weights
// loaded once per block, reused x4 in registers), partials reduced via LDS.
// Cuts the Wh L2 stream 4x (r10: 26 TB/s through L2, ~75% of ceiling).
// Candidate gathers stay per-wave and barrier-free.
__global__ __launch_bounds__(256) void walk_kernel(
    const int*   __restrict__ nbrs,  const float* __restrict__ noise,
    const float* __restrict__ XGfP,  const float* __restrict__ dWhP,
    const float* __restrict__ dbh,   const float* __restrict__ dWo,
    const float* __restrict__ dbo,
    int* __restrict__ paths, int* __restrict__ fail_cnt, int* __restrict__ fail_list,
    float* __restrict__ out)
{
    __shared__ float hf_s[4][HD];            // h of the block's 4 nodes
    __shared__ float part_s[4][4][6][64];    // [writer wave][node][m][lane] 24 KB

    const int wid  = threadIdx.x >> 6;
    const int lane = threadIdx.x & 63;
    const int node = blockIdx.x*4 + wid;

    float h0 = 0.f, h1 = 0.f;
    float dbhf[6], hgf[6];
#pragma unroll
    for (int m=0;m<6;m++){ dbhf[m] = dbh[lane+64*m]; hgf[m] = dbhf[m]; }
    const float wo0f0 = dWo[lane*CD];          // dWo[:,0] lane-local
    const float wo0f1 = dWo[(lane+64)*CD];
    const float dbo0f = dbo[0];

    int  cur = node;
    int  ch0=0, ch1=0, ch2=0, ch3=0;
    bool pushed = false;

    for (int t=0;t<TT;t++){
        if      (t==0) ch0 = cur;
        else if (t==1) ch1 = cur;
        else if (t==2) ch2 = cur;
        else           ch3 = cur;

        // ---- extend prefix (packed row: 2 x b128) ----
        {
            const float4* xr = (const float4*)(XGfP + ((size_t)cur*64 + lane)*8);
            const float4 A = xr[0], B = xr[1];
            float r = fsig (A.x + hgf[0]);
            float z = fsig (A.z + hgf[2]);
            float n = ftanh(B.x + r*hgf[4]);
            h0 = (1.f-z)*n + z*h0;
            r = fsig (A.y + hgf[1]);
            z = fsig (A.w + hgf[3]);
            n = ftanh(B.y + r*hgf[5]);
            h1 = (1.f-z)*n + z*h1;
        }
        hf_s[wid][lane] = h0;  hf_s[wid][lane+64] = h1;
        __syncthreads();                 // (1) all 4 nodes' h visible

        // ---- cooperative matvec: wave wid covers k = 32*wid .. 32*wid+31 ----
        {
            float pacc[4][6];
#pragma unroll
            for (int j=0;j<4;j++)
#pragma unroll
                for (int m=0;m<6;m++) pacc[j][m] = 0.f;
            const float4* wr = (const float4*)(dWhP + (size_t)lane*8);
#pragma unroll 4
            for (int kk=0; kk<32; kk++){
                const int k = wid*32 + kk;
                const float4 W0 = wr[k*128], W1 = wr[k*128+1];
#pragma unroll
                for (int j=0;j<4;j++){
                    const float hk = hf_s[j][k];
                    pacc[j][0] += hk*W0.x; pacc[j][1] += hk*W0.y;
                    pacc[j][2] += hk*W0.z; pacc[j][3] += hk*W0.w;
                    pacc[j][4] += hk*W1.x; pacc[j][5] += hk*W1.y;
                }
            }
#pragma unroll
            for (int j=0;j<4;j++)
#pragma unroll
                for (int m=0;m<6;m++) part_s[wid][j][m][lane] = pacc[j][m];
        }
        __syncthreads();                 // (2) partials visible

#pragma unroll
        for (int m=0;m<6;m++)
            hgf[m] = dbhf[m] + part_s[0][wid][m][lane] + part_s[1][wid][m][lane]
                             + part_s[2][wid][m][lane] + part_s[3][wid][m][lane];

        // ---- 16 candidates, 4 groups of 4 with prefetch (per-wave, no barriers) ----
        int   nbrv = (lane < DG) ? nbrs[(size_t)cur*DG + lane] : 0;
        float nz   = (lane < DG) ? noise[((size_t)t*NN + node)*DG + lane] : 0.f;
        float lf = -3.0e38f;
#pragma unroll
        for (int g=0; g<4; g++){
            float4 CA[4], CB[4];
#pragma unroll
            for (int j=0;j<4;j++){
                const int nd = __shfl(nbrv, g*4+j);
                const float4* cr = (const float4*)(XGfP + ((size_t)nd*64 + lane)*8);
                CA[j] = cr[0];  CB[j] = cr[1];
            }
            float part[4];
#pragma unroll
            for (int j=0;j<4;j++){
                float r = fsig (CA[j].x + hgf[0]);
                float z = fsig (CA[j].z + hgf[2]);
                float n = ftanh(CB[j].x + r*hgf[4]);
                part[j]  = ((1.f-z)*n + z*h0) * wo0f0;
                r = fsig (CA[j].y + hgf[1]);
                z = fsig (CA[j].w + hgf[3]);
                n = ftanh(CB[j].y + r*hgf[5]);
                part[j] += ((1.f-z)*n + z*h1) * wo0f1;
            }
#pragma unroll
            for (int off=32; off>0; off>>=1){
#pragma unroll
                for (int j=0;j<4;j++) part[j] += __shfl_xor(part[j], off);
            }
#pragma unroll
            for (int j=0;j<4;j++) if (lane == g*4+j) lf = part[j] + dbo0f;
        }

        // ---- softmax + noisy argmax + top-2 margin ----
        float v  = (lane < DG) ? lf : -3.0e38f;
        float mx = v;
#pragma unroll
        for (int off=32; off>0; off>>=1) mx = fmaxf(mx, __shfl_xor(mx, off));
        float e = (lane < DG) ? __expf(v - mx) : 0.f;
        float s = e;
#pragma unroll
        for (int off=32; off>0; off>>=1) s += __shfl_xor(s, off);
        const float normf = mx + __logf(s);

        float noisyf = (lane < DG) ? __expf(v - normf) + 0.01f*nz : -3.0e38f;
        int   idx = lane;
        float bv  = noisyf;
#pragma unroll
        for (int off=32; off>0; off>>=1){
            float ov = __shfl_xor(bv, off);
            int   oi = __shfl_xor(idx, off);
            if (ov > bv || (ov == bv && oi < idx)){ bv = ov; idx = oi; }
        }
        float sv = (lane == idx || lane >= DG) ? -3.0e38f : noisyf;
#pragma unroll
        for (int off=32; off>0; off>>=1) sv = fmaxf(sv, __shfl_xor(sv, off));

        const bool trip = (bv - sv) < MARGIN;   // wave-uniform
        if (trip && !pushed && lane == 0){
            const int slot = atomicAdd(fail_cnt, 1);
            if (slot < NN) fail_list[slot] = node;
        }
        pushed = pushed || trip;

        const float lpf = __shfl(v, idx) - normf;
        if (lane == 0) out[NN*CD + node*TT + t] = lpf;
        cur = __shfl(nbrv, idx);
    }

    if (lane == 0){
        int* p = paths + (size_t)node*8;
        p[0]=ch0; p[1]=ch1; p[2]=ch2; p[3]=ch3; p[4]=cur;
    }
}

// Phase 2: exact-f64 full-walk redo, WAVE PER NODE, no barriers (r10, passing).
__global__ __launch_bounds__(256) void fix_kernel(
    const int*   __restrict__ nbrs,  const float* __restrict__ noise,
    const float* __restrict__ XGfP,  const float* __restrict__ XGrP,
    const float* __restrict__ dWhP,  const float* __restrict__ dbh,
    const float* __restrict__ dWo,   const float* __restrict__ dbo,
    const int* __restrict__ fail_cnt, const int* __restrict__ fail_list,
    int* __restrict__ paths, float* __restrict__ out)
{
    __shared__ double h_s[4][HD];
    const int wid  = threadIdx.x >> 6;
    const int lane = threadIdx.x & 63;
    const int nw   = gridDim.x * 4;
    const int count = min(fail_cnt[0], NN);

    double db64[6];
#pragma unroll
    for (int m=0;m<6;m++) db64[m] = (double)dbh[lane+64*m];
    const double wo0d0 = (double)dWo[lane*CD];
    const double wo0d1 = (double)dWo[(lane+64)*CD];
    const double dbo0d = (double)dbo[0];

    for (int ii = blockIdx.x*4 + wid; ii < count; ii += nw){
        const int node = fail_list[ii];
        double H0 = 0.0, H1 = 0.0;
        double g64[6];
#pragma unroll
        for (int m=0;m<6;m++) g64[m] = db64[m];
        int cur = node;
        int c0=0,c1=0,c2=0,c3=0;

        for (int t=0;t<TT;t++){
            if      (t==0) c0 = cur;
            else if (t==1) c1 = cur;
            else if (t==2) c2 = cur;
            else           c3 = cur;

            // ---- extend (f64 = hi + residual) ----
            {
                const size_t base = (size_t)cur*64 + lane;
                const float* hi = XGfP + base*8;
                const float* lo = XGrP + base*6;
                double r = sig64f (((double)hi[0]+(double)lo[0]) + g64[0]);
                double z = sig64f (((double)hi[2]+(double)lo[2]) + g64[2]);
                double n = tanh64f(((double)hi[4]+(double)lo[4]) + r*g64[4]);
                H0 = (1.0-z)*n + z*H0;
                r = sig64f (((double)hi[1]+(double)lo[1]) + g64[1]);
                z = sig64f (((double)hi[3]+(double)lo[3]) + g64[3]);
                n = tanh64f(((double)hi[5]+(double)lo[5]) + r*g64[5]);
                H1 = (1.0-z)*n + z*H1;
            }
            h_s[wid][lane] = H0;  h_s[wid][lane+64] = H1;   // own-wave only

            // ---- matvec f64 (packed weights, 2 x b128 per k; exact cvt) ----
#pragma unroll
            for (int m=0;m<6;m++) g64[m] = db64[m];
            {
                const float4* wr = (const float4*)(dWhP + (size_t)lane*8);
                for (int k=0;k<HD;k++){
                    const double hk = h_s[wid][k];
                    const float4 W0 = wr[k*128], W1 = wr[k*128+1];
                    g64[0] += hk*(double)W0.x; g64[1] += hk*(double)W0.y;
                    g64[2] += hk*(double)W0.z; g64[3] += hk*(double)W0.w;
                    g64[4] += hk*(double)W1.x; g64[5] += hk*(double)W1.y;
                }
            }

            // ---- 16 candidates f64, 4 groups of 4 with prefetch ----
            int   nbrv = (lane < DG) ? nbrs[(size_t)cur*DG + lane] : 0;
            float nz   = (lane < DG) ? noise[((size_t)t*NN + node)*DG + lane] : 0.f;
            double lv = -1e300;
#pragma unroll
            for (int g=0; g<4; g++){
                float ch[4][6], cl[4][6];
#pragma unroll
                for (int j=0;j<4;j++){
                    const int nd = __shfl(nbrv, g*4+j);
                    const size_t base = (size_t)nd*64 + lane;
                    const float* hi = XGfP + base*8;
                    const float* lo = XGrP + base*6;
#pragma unroll
                    for (int q=0;q<6;q++){ ch[j][q]=hi[q]; cl[j][q]=lo[q]; }
                }
#pragma unroll
                for (int j=0;j<4;j++){
                    double r = sig64f (((double)ch[j][0]+(double)cl[j][0]) + g64[0]);
                    double z = sig64f (((double)ch[j][2]+(double)cl[j][2]) + g64[2]);
                    double n = tanh64f(((double)ch[j][4]+(double)cl[j][4]) + r*g64[4]);
                    double part = ((1.0-z)*n + z*H0) * wo0d0;
                    r = sig64f (((double)ch[j][1]+(double)cl[j][1]) + g64[1]);
                    z = sig64f (((double)ch[j][3]+(double)cl[j][3]) + g64[3]);
                    n = tanh64f(((double)ch[j][5]+(double)cl[j][5]) + r*g64[5]);
                    part += ((1.0-z)*n + z*H1) * wo0d1;
#pragma unroll
                    for (int off=32; off>0; off>>=1) part += __shfl_xor(part, off);
                    if (lane == g*4+j) lv = part + dbo0d;
                }
            }

            // ---- softmax + noisy argmax ----
            double dv = (lane < DG) ? lv : -1e300;
            double dmx = dv;
#pragma unroll
            for (int off=32; off>0; off>>=1) dmx = fmax(dmx, __shfl_xor(dmx, off));
            double de = (lane < DG) ? fexp64(dv - dmx) : 0.0;
            double ds = de;
#pragma unroll
            for (int off=32; off>0; off>>=1) ds += __shfl_xor(ds, off);
            const double dnorm = dmx + log(ds);
            double dnoisy = (lane < DG) ? fexp64(dv - dnorm) + 0.01*(double)nz : -1e300;
            int di = lane;
#pragma unroll
            for (int off=32; off>0; off>>=1){
                double ov = __shfl_xor(dnoisy, off);
                int    oi = __shfl_xor(di, off);
                if (ov > dnoisy || (ov == dnoisy && oi < di)){ dnoisy = ov; di = oi; }
            }
            const double lpfix = __shfl(dv, di) - dnorm;
            if (lane == 0) out[NN*CD + node*TT + t] = (float)lpfix;
            cur = __shfl(nbrv, di);
        }
        if (lane == 0){
            int* p = paths + (size_t)node*8;
            p[0]=c0; p[1]=c1; p[2]=c2; p[3]=c3; p[4]=cur;
        }
    }
}

// w-GRU over the recorded 5-node walk; block-cooperative matvec (same 4x L2 cut).
__global__ __launch_bounds__(256) void wgru_kernel(
    const int*   __restrict__ paths, const float* __restrict__ XGwP,
    const float* __restrict__ wWhP,  const float* __restrict__ wbh,
    const float* __restrict__ wWo,   const float* __restrict__ wbo,
    float* __restrict__ out)
{
    __shared__ float hw_s[4][HD];
    __shared__ float part_s[4][4][6][64];
    const int wid  = threadIdx.x >> 6;
    const int lane = threadIdx.x & 63;
    const int node = blockIdx.x*4 + wid;

    float h0 = 0.f, h1 = 0.f;
    float wb[6], hg[6];
#pragma unroll
    for (int m=0;m<6;m++){ wb[m] = wbh[lane+64*m]; hg[m] = wb[m]; }
    const int* p = paths + (size_t)node*8;

#pragma unroll
    for (int s=0; s<=TT; s++){
        const int c = p[s];
        const float4* xr = (const float4*)(XGwP + ((size_t)c*64 + lane)*8);
        const float4 A = xr[0], B = xr[1];
        float r = fsig (A.x + hg[0]);
        float z = fsig (A.z + hg[2]);
        float n = ftanh(B.x + r*hg[4]);
        h0 = (1.f-z)*n + z*h0;
        r = fsig (A.y + hg[1]);
        z = fsig (A.w + hg[3]);
        n = ftanh(B.y + r*hg[5]);
        h1 = (1.f-z)*n + z*h1;
        if (s < TT){
            hw_s[wid][lane] = h0;  hw_s[wid][lane+64] = h1;
            __syncthreads();
            float pacc[4][6];
#pragma unroll
            for (int j=0;j<4;j++)
#pragma unroll
                for (int m=0;m<6;m++) pacc[j][m] = 0.f;
            const float4* wr = (const float4*)(wWhP + (size_t)lane*8);
#pragma unroll 4
            for (int kk=0; kk<32; kk++){
                const int k = wid*32 + kk;
                const float4 W0 = wr[k*128], W1 = wr[k*128+1];
#pragma unroll
                for (int j=0;j<4;j++){
                    const float hk = hw_s[j][k];
                    pacc[j][0] += hk*W0.x; pacc[j][1] += hk*W0.y;
                    pacc[j][2] += hk*W0.z; pacc[j][3] += hk*W0.w;
                    pacc[j][4] += hk*W1.x; pacc[j][5] += hk*W1.y;
                }
            }
#pragma unroll
            for (int j=0;j<4;j++)
#pragma unroll
                for (int m=0;m<6;m++) part_s[wid][j][m][lane] = pacc[j][m];
            __syncthreads();
#pragma unroll
            for (int m=0;m<6;m++)
                hg[m] = wb[m] + part_s[0][wid][m][lane] + part_s[1][wid][m][lane]
                              + part_s[2][wid][m][lane] + part_s[3][wid][m][lane];
        }
    }
    hw_s[wid][lane] = h0;  hw_s[wid][lane+64] = h1;
    __syncthreads();

    float acc = wbo[lane];                 // CD == 64 == wave width
    const float* wcol = wWo + lane;
    for (int i=0;i<HD;i++) acc += hw_s[wid][i] * wcol[(size_t)i*CD];
    out[(size_t)node*CD + lane] = acc;
}

extern "C" void kernel_launch(void* const* d_in, const int* in_sizes, int n_in,
                              void* d_out, int out_size, void* d_ws, size_t ws_size,
                              hipStream_t stream)
{
    const float* attr  = (const float*)d_in[0];
    const int*   nbrs  = (const int*)  d_in[1];
    const float* noise = (const float*)d_in[2];
    const float* dWx = (const float*)d_in[3];
    const float* dWh = (const float*)d_in[4];
    const float* dbx = (const float*)d_in[5];
    const float* dbh = (const float*)d_in[6];
    const float* dWo = (const float*)d_in[7];
    const float* dbo = (const float*)d_in[8];
    const float* wWx = (const float*)d_in[9];
    const float* wWh = (const float*)d_in[10];
    const float* wbx = (const float*)d_in[11];
    const float* wbh = (const float*)d_in[12];
    const float* wWo = (const float*)d_in[13];
    const float* wbo = (const float*)d_in[14];
    float* out = (float*)d_out;

    char* ws = (char*)d_ws;
    float* XGfP      = (float*)(ws);                 // 8000*64*8*4 = 16,384,000 B
    float* XGrP      = (float*)(ws + 16384000);      // 8000*64*6*4 = 12,288,000 B
    float* XGwP      = (float*)(ws + 28672000);      // 16,384,000 B
    float* dWhP      = (float*)(ws + 45056000);      // 262,144 B
    float* wWhP      = (float*)(ws + 45318144);      // 262,144 B
    int*   paths     = (int*)  (ws + 45580288);      // 256,000 B
    int*   fail_list = (int*)  (ws + 45836288);      // 32,000 B
    int*   fail_cnt  = (int*)  (ws + 45868288);      // 4 B   (total ~45.9 MB)

    hipMemsetAsync(fail_cnt, 0, sizeof(int), stream);

    xg_kernel<<<NN/8, G3, 0, stream>>>(attr, dWx, dbx, XGfP, XGrP);
    xg_kernel<<<NN/8, G3, 0, stream>>>(attr, wWx, wbx, XGwP, nullptr);
    repack_kernel<<<(HD*64*8)/256, 256, 0, stream>>>(dWh, dWhP);
    repack_kernel<<<(HD*64*8)/256, 256, 0, stream>>>(wWh, wWhP);

    walk_kernel<<<NN/4, 256, 0, stream>>>(nbrs, noise, XGfP, dWhP,
                                          dbh, dWo, dbo,
                                          paths, fail_cnt, fail_list, out);
    fix_kernel<<<2000, 256, 0, stream>>>(nbrs, noise, XGfP, XGrP,
                                         dWhP, dbh, dWo, dbo,
                                         fail_cnt, fail_list, paths, out);
    wgru_kernel<<<NN/4, 256, 0, stream>>>(paths, XGwP, wWhP, wbh, wWo, wbo, out);
}

// Round 12
// 600.625 us; speedup vs baseline: 6.7778x; 1.0233x over previous
//
#include <hip/hip_runtime.h>
#include <math.h>

#define NN 8000   // nodes
#define CD 64     // node feature dim / C_OUT
#define DG 16     // neighbors per node
#define HD 128    // GRU hidden
#define G3 384    // 3*HD
#define TT 4      // walk steps
// Worst-case f32 noisy-score error bound ~1e-3; MARGIN = 4e-3 (proven r8-r11).
#define MARGIN 4e-3f

#if __has_builtin(__builtin_amdgcn_rcpf)
#define RCP(x) __builtin_amdgcn_rcpf(x)
#else
#define RCP(x) (1.f/(x))
#endif

// fast f32 (walk + wgru; error ~1e-6 << MARGIN)
__device__ __forceinline__ float fsig (float x){ return RCP(1.f + __expf(-x)); }
__device__ __forceinline__ float ftanh(float x){ return 1.f - 2.f*RCP(1.f + __expf(2.f*x)); }

// fast f64 exp: range-reduced 13-term Horner, ~3 ulp (validated r9-r11).
__device__ __forceinline__ double fexp64(double x){
    const double LOG2E  = 1.4426950408889634074;
    const double LN2_HI = 6.93147180369123816490e-01;
    const double LN2_LO = 1.90821492927058770002e-10;
    x = fmin(fmax(x, -700.0), 700.0);
    double fn = rint(x * LOG2E);
    double r  = fma(-fn, LN2_HI, x);
    r = fma(-fn, LN2_LO, r);
    double p = 1.6059043836821613e-10;            // 1/13!
    p = fma(p, r, 2.0876756987868099e-09);
    p = fma(p, r, 2.5052108385441719e-08);
    p = fma(p, r, 2.7557319223985893e-07);
    p = fma(p, r, 2.7557319223985888e-06);
    p = fma(p, r, 2.4801587301587302e-05);
    p = fma(p, r, 1.9841269841269841e-04);
    p = fma(p, r, 1.3888888888888889e-03);
    p = fma(p, r, 8.3333333333333332e-03);
    p = fma(p, r, 4.1666666666666664e-02);
    p = fma(p, r, 1.6666666666666666e-01);
    p = fma(p, r, 0.5);
    p = fma(p, r, 1.0);
    p = fma(p, r, 1.0);
    long long bits = __double_as_longlong(p) + ((long long)(int)fn << 52);
    return __longlong_as_double(bits);
}
__device__ __forceinline__ double sig64f (double x){ return 1.0/(1.0 + fexp64(-x)); }
__device__ __forceinline__ double tanh64f(double x){ return 1.0 - 2.0/(fexp64(2.0*x) + 1.0); }

// XG precompute in f64; emit packed-hi [n][64][8] (+ optional residual [n][64][6]).
// Slot q of lane l holds XG[n][64*q + l]; matches hg[m] register order.
__global__ __launch_bounds__(384) void xg_kernel(const float* __restrict__ A,
    const float* __restrict__ W, const float* __restrict__ b,
    float* __restrict__ hiP, float* __restrict__ loP)
{
    __shared__ float a_s[8][64];
    const int g  = threadIdx.x;        // 0..383
    const int l  = g & 63, q = g >> 6;
    const int n0 = blockIdx.x * 8;
    for (int idx = threadIdx.x; idx < 8*64; idx += 384)
        a_s[idx>>6][idx&63] = A[(size_t)n0*64 + idx];
    __syncthreads();
    double acc[8];
    const double bg = (double)b[g];
#pragma unroll
    for (int j=0;j<8;j++) acc[j] = bg;
    for (int c=0;c<64;c++){
        const double w = (double)W[c*G3 + g];
#pragma unroll
        for (int j=0;j<8;j++) acc[j] += (double)a_s[j][c]*w;
    }
#pragma unroll
    for (int j=0;j<8;j++){
        const size_t base = (size_t)(n0+j)*64 + l;
        const float hi = (float)acc[j];
        hiP[base*8 + q] = hi;
        if (q < 2) hiP[base*8 + 6 + q] = 0.f;       // zero pad slots
        if (loP) loP[base*6 + q] = (float)(acc[j] - (double)hi);
    }
}

// Repack Wh [k][384] -> [k][lane][8] (slot m = W[k][64*m+lane], slots 6,7 = 0).
__global__ __launch_bounds__(256) void repack_kernel(const float* __restrict__ W,
                                                     float* __restrict__ P)
{
    const int idx = blockIdx.x*256 + threadIdx.x;   // 0 .. 128*512-1
    const int k = idx >> 9, rem = idx & 511, l = rem >> 3, s = rem & 7;
    P[idx] = (s < 6) ? W[k*G3 + s*64 + l] : 0.f;
}

// Phase 1: pure-f32 walk. 4 waves = 4 nodes per block; block-cooperative
// matvec (4x L2 cut, r11). First margin trip records (node, t0) for the
// fixup kernel; pre-trip selections are certified exact.
__global__ __launch_bounds__(256) void walk_kernel(
    const int*   __restrict__ nbrs,  const float* __restrict__ noise,
    const float* __restrict__ XGfP,  const float* __restrict__ dWhP,
    const float* __restrict__ dbh,   const float* __restrict__ dWo,
    const float* __restrict__ dbo,
    int* __restrict__ paths, int* __restrict__ fail_cnt, int* __restrict__ fail_list,
    float* __restrict__ out)
{
    __shared__ float hf_s[4][HD];            // h of the block's 4 nodes
    __shared__ float part_s[4][4][6][64];    // [writer wave][node][m][lane] 24 KB

    const int wid  = threadIdx.x >> 6;
    const int lane = threadIdx.x & 63;
    const int node = blockIdx.x*4 + wid;

    float h0 = 0.f, h1 = 0.f;
    float dbhf[6], hgf[6];
#pragma unroll
    for (int m=0;m<6;m++){ dbhf[m] = dbh[lane+64*m]; hgf[m] = dbhf[m]; }
    const float wo0f0 = dWo[lane*CD];          // dWo[:,0] lane-local
    const float wo0f1 = dWo[(lane+64)*CD];
    const float dbo0f = dbo[0];

    int  cur = node;
    int  ch0=0, ch1=0, ch2=0, ch3=0;
    bool pushed = false;

    for (int t=0;t<TT;t++){
        if      (t==0) ch0 = cur;
        else if (t==1) ch1 = cur;
        else if (t==2) ch2 = cur;
        else           ch3 = cur;

        // ---- extend prefix (packed row: 2 x b128) ----
        {
            const float4* xr = (const float4*)(XGfP + ((size_t)cur*64 + lane)*8);
            const float4 A = xr[0], B = xr[1];
            float r = fsig (A.x + hgf[0]);
            float z = fsig (A.z + hgf[2]);
            float n = ftanh(B.x + r*hgf[4]);
            h0 = (1.f-z)*n + z*h0;
            r = fsig (A.y + hgf[1]);
            z = fsig (A.w + hgf[3]);
            n = ftanh(B.y + r*hgf[5]);
            h1 = (1.f-z)*n + z*h1;
        }
        hf_s[wid][lane] = h0;  hf_s[wid][lane+64] = h1;
        __syncthreads();                 // (1) all 4 nodes' h visible

        // ---- cooperative matvec: wave wid covers k = 32*wid .. 32*wid+31 ----
        {
            float pacc[4][6];
#pragma unroll
            for (int j=0;j<4;j++)
#pragma unroll
                for (int m=0;m<6;m++) pacc[j][m] = 0.f;
            const float4* wr = (const float4*)(dWhP + (size_t)lane*8);
#pragma unroll 4
            for (int kk=0; kk<32; kk++){
                const int k = wid*32 + kk;
                const float4 W0 = wr[k*128], W1 = wr[k*128+1];
#pragma unroll
                for (int j=0;j<4;j++){
                    const float hk = hf_s[j][k];
                    pacc[j][0] += hk*W0.x; pacc[j][1] += hk*W0.y;
                    pacc[j][2] += hk*W0.z; pacc[j][3] += hk*W0.w;
                    pacc[j][4] += hk*W1.x; pacc[j][5] += hk*W1.y;
                }
            }
#pragma unroll
            for (int j=0;j<4;j++)
#pragma unroll
                for (int m=0;m<6;m++) part_s[wid][j][m][lane] = pacc[j][m];
        }
        __syncthreads();                 // (2) partials visible

#pragma unroll
        for (int m=0;m<6;m++)
            hgf[m] = dbhf[m] + part_s[0][wid][m][lane] + part_s[1][wid][m][lane]
                             + part_s[2][wid][m][lane] + part_s[3][wid][m][lane];

        // ---- 16 candidates, 4 groups of 4 with prefetch (per-wave, no barriers) ----
        int   nbrv = (lane < DG) ? nbrs[(size_t)cur*DG + lane] : 0;
        float nz   = (lane < DG) ? noise[((size_t)t*NN + node)*DG + lane] : 0.f;
        float lf = -3.0e38f;
#pragma unroll
        for (int g=0; g<4; g++){
            float4 CA[4], CB[4];
#pragma unroll
            for (int j=0;j<4;j++){
                const int nd = __shfl(nbrv, g*4+j);
                const float4* cr = (const float4*)(XGfP + ((size_t)nd*64 + lane)*8);
                CA[j] = cr[0];  CB[j] = cr[1];
            }
            float part[4];
#pragma unroll
            for (int j=0;j<4;j++){
                float r = fsig (CA[j].x + hgf[0]);
                float z = fsig (CA[j].z + hgf[2]);
                float n = ftanh(CB[j].x + r*hgf[4]);
                part[j]  = ((1.f-z)*n + z*h0) * wo0f0;
                r = fsig (CA[j].y + hgf[1]);
                z = fsig (CA[j].w + hgf[3]);
                n = ftanh(CB[j].y + r*hgf[5]);
                part[j] += ((1.f-z)*n + z*h1) * wo0f1;
            }
#pragma unroll
            for (int off=32; off>0; off>>=1){
#pragma unroll
                for (int j=0;j<4;j++) part[j] += __shfl_xor(part[j], off);
            }
#pragma unroll
            for (int j=0;j<4;j++) if (lane == g*4+j) lf = part[j] + dbo0f;
        }

        // ---- softmax + noisy argmax + top-2 margin ----
        float v  = (lane < DG) ? lf : -3.0e38f;
        float mx = v;
#pragma unroll
        for (int off=32; off>0; off>>=1) mx = fmaxf(mx, __shfl_xor(mx, off));
        float e = (lane < DG) ? __expf(v - mx) : 0.f;
        float s = e;
#pragma unroll
        for (int off=32; off>0; off>>=1) s += __shfl_xor(s, off);
        const float normf = mx + __logf(s);

        float noisyf = (lane < DG) ? __expf(v - normf) + 0.01f*nz : -3.0e38f;
        int   idx = lane;
        float bv  = noisyf;
#pragma unroll
        for (int off=32; off>0; off>>=1){
            float ov = __shfl_xor(bv, off);
            int   oi = __shfl_xor(idx, off);
            if (ov > bv || (ov == bv && oi < idx)){ bv = ov; idx = oi; }
        }
        float sv = (lane == idx || lane >= DG) ? -3.0e38f : noisyf;
#pragma unroll
        for (int off=32; off>0; off>>=1) sv = fmaxf(sv, __shfl_xor(sv, off));

        const bool trip = (bv - sv) < MARGIN;   // wave-uniform
        if (trip && !pushed){
            if (lane == 0){
                const int slot = atomicAdd(fail_cnt, 1);
                if (slot < NN) fail_list[slot] = node | (t << 16);  // first trip step
            }
            pushed = true;
        }

        const float lpf = __shfl(v, idx) - normf;
        if (lane == 0) out[NN*CD + node*TT + t] = lpf;
        cur = __shfl(nbrv, idx);
    }

    if (lane == 0){
        int* p = paths + (size_t)node*8;
        p[0]=ch0; p[1]=ch1; p[2]=ch2; p[3]=ch3; p[4]=cur;
    }
}

// Phase 2: exact-f64 redo, WAVE PER NODE, no barriers (r10/r11 structure).
// NEW (r12): replays steps t < t0 as hidden-only updates along the certified
// path (no candidate gathers / scoring); full f64 scoring only from t0 on.
__global__ __launch_bounds__(256) void fix_kernel(
    const int*   __restrict__ nbrs,  const float* __restrict__ noise,
    const float* __restrict__ XGfP,  const float* __restrict__ XGrP,
    const float* __restrict__ dWhP,  const float* __restrict__ dbh,
    const float* __restrict__ dWo,   const float* __restrict__ dbo,
    const int* __restrict__ fail_cnt, const int* __restrict__ fail_list,
    int* __restrict__ paths, float* __restrict__ out)
{
    __shared__ double h_s[4][HD];
    const int wid  = threadIdx.x >> 6;
    const int lane = threadIdx.x & 63;
    const int nw   = gridDim.x * 4;
    const int count = min(fail_cnt[0], NN);

    double db64[6];
#pragma unroll
    for (int m=0;m<6;m++) db64[m] = (double)dbh[lane+64*m];
    const double wo0d0 = (double)dWo[lane*CD];
    const double wo0d1 = (double)dWo[(lane+64)*CD];
    const double dbo0d = (double)dbo[0];

    for (int ii = blockIdx.x*4 + wid; ii < count; ii += nw){
        const int entry = fail_list[ii];
        const int node  = entry & 0xFFFF;
        const int t0    = entry >> 16;
        const int* pw   = paths + (size_t)node*8;   // entries 0..t0 certified exact

        double H0 = 0.0, H1 = 0.0;
        double g64[6];
#pragma unroll
        for (int m=0;m<6;m++) g64[m] = db64[m];
        int cur = node;
        int c0=0,c1=0,c2=0,c3=0;

        for (int t=0;t<TT;t++){
            if      (t==0) c0 = cur;
            else if (t==1) c1 = cur;
            else if (t==2) c2 = cur;
            else           c3 = cur;

            // ---- extend (f64 = hi + residual) ----
            {
                const size_t base = (size_t)cur*64 + lane;
                const float* hi = XGfP + base*8;
                const float* lo = XGrP + base*6;
                double r = sig64f (((double)hi[0]+(double)lo[0]) + g64[0]);
                double z = sig64f (((double)hi[2]+(double)lo[2]) + g64[2]);
                double n = tanh64f(((double)hi[4]+(double)lo[4]) + r*g64[4]);
                H0 = (1.0-z)*n + z*H0;
                r = sig64f (((double)hi[1]+(double)lo[1]) + g64[1]);
                z = sig64f (((double)hi[3]+(double)lo[3]) + g64[3]);
                n = tanh64f(((double)hi[5]+(double)lo[5]) + r*g64[5]);
                H1 = (1.0-z)*n + z*H1;
            }
            h_s[wid][lane] = H0;  h_s[wid][lane+64] = H1;   // own-wave only

            // ---- matvec f64 (packed weights, 2 x b128 per k; exact cvt) ----
#pragma unroll
            for (int m=0;m<6;m++) g64[m] = db64[m];
            {
                const float4* wr = (const float4*)(dWhP + (size_t)lane*8);
                for (int k=0;k<HD;k++){
                    const double hk = h_s[wid][k];
                    const float4 W0 = wr[k*128], W1 = wr[k*128+1];
                    g64[0] += hk*(double)W0.x; g64[1] += hk*(double)W0.y;
                    g64[2] += hk*(double)W0.z; g64[3] += hk*(double)W0.w;
                    g64[4] += hk*(double)W1.x; g64[5] += hk*(double)W1.y;
                }
            }

            // ---- certified prefix: skip scoring, follow recorded path ----
            if (t < t0){
                cur = pw[t+1];
                continue;
            }

            // ---- 16 candidates f64, 4 groups of 4 with prefetch ----
            int   nbrv = (lane < DG) ? nbrs[(size_t)cur*DG + lane] : 0;
            float nz   = (lane < DG) ? noise[((size_t)t*NN + node)*DG + lane] : 0.f;
            double lv = -1e300;
#pragma unroll
            for (int g=0; g<4; g++){
                float ch[4][6], cl[4][6];
#pragma unroll
                for (int j=0;j<4;j++){
                    const int nd = __shfl(nbrv, g*4+j);
                    const size_t base = (size_t)nd*64 + lane;
                    const float* hi = XGfP + base*8;
                    const float* lo = XGrP + base*6;
#pragma unroll
                    for (int q=0;q<6;q++){ ch[j][q]=hi[q]; cl[j][q]=lo[q]; }
                }
#pragma unroll
                for (int j=0;j<4;j++){
                    double r = sig64f (((double)ch[j][0]+(double)cl[j][0]) + g64[0]);
                    double z = sig64f (((double)ch[j][2]+(double)cl[j][2]) + g64[2]);
                    double n = tanh64f(((double)ch[j][4]+(double)cl[j][4]) + r*g64[4]);
                    double part = ((1.0-z)*n + z*H0) * wo0d0;
                    r = sig64f (((double)ch[j][1]+(double)cl[j][1]) + g64[1]);
                    z = sig64f (((double)ch[j][3]+(double)cl[j][3]) + g64[3]);
                    n = tanh64f(((double)ch[j][5]+(double)cl[j][5]) + r*g64[5]);
                    part += ((1.0-z)*n + z*H1) * wo0d1;
#pragma unroll
                    for (int off=32; off>0; off>>=1) part += __shfl_xor(part, off);
                    if (lane == g*4+j) lv = part + dbo0d;
                }
            }

            // ---- softmax + noisy argmax (identical numerics to r9-r11) ----
            double dv = (lane < DG) ? lv : -1e300;
            double dmx = dv;
#pragma unroll
            for (int off=32; off>0; off>>=1) dmx = fmax(dmx, __shfl_xor(dmx, off));
            double de = (lane < DG) ? fexp64(dv - dmx) : 0.0;
            double ds = de;
#pragma unroll
            for (int off=32; off>0; off>>=1) ds += __shfl_xor(ds, off);
            const double dnorm = dmx + log(ds);
            double dnoisy = (lane < DG) ? fexp64(dv - dnorm) + 0.01*(double)nz : -1e300;
            int di = lane;
#pragma unroll
            for (int off=32; off>0; off>>=1){
                double ov = __shfl_xor(dnoisy, off);
                int    oi = __shfl_xor(di, off);
                if (ov > dnoisy || (ov == dnoisy && oi < di)){ dnoisy = ov; di = oi; }
            }
            const double lpfix = __shfl(dv, di) - dnorm;
            if (lane == 0) out[NN*CD + node*TT + t] = (float)lpfix;
            cur = __shfl(nbrv, di);
        }
        if (lane == 0){
            int* p = paths + (size_t)node*8;
            p[0]=c0; p[1]=c1; p[2]=c2; p[3]=c3; p[4]=cur;
        }
    }
}

// w-GRU over the recorded 5-node walk; block-cooperative matvec (r11).
__global__ __launch_bounds__(256) void wgru_kernel(
    const int*   __restrict__ paths, const float* __restrict__ XGwP,
    const float* __restrict__ wWhP,  const float* __restrict__ wbh,
    const float* __restrict__ wWo,   const float* __restrict__ wbo,
    float* __restrict__ out)
{
    __shared__ float hw_s[4][HD];
    __shared__ float part_s[4][4][6][64];
    const int wid  = threadIdx.x >> 6;
    const int lane = threadIdx.x & 63;
    const int node = blockIdx.x*4 + wid;

    float h0 = 0.f, h1 = 0.f;
    float wb[6], hg[6];
#pragma unroll
    for (int m=0;m<6;m++){ wb[m] = wbh[lane+64*m]; hg[m] = wb[m]; }
    const int* p = paths + (size_t)node*8;

#pragma unroll
    for (int s=0; s<=TT; s++){
        const int c = p[s];
        const float4* xr = (const float4*)(XGwP + ((size_t)c*64 + lane)*8);
        const float4 A = xr[0], B = xr[1];
        float r = fsig (A.x + hg[0]);
        float z = fsig (A.z + hg[2]);
        float n = ftanh(B.x + r*hg[4]);
        h0 = (1.f-z)*n + z*h0;
        r = fsig (A.y + hg[1]);
        z = fsig (A.w + hg[3]);
        n = ftanh(B.y + r*hg[5]);
        h1 = (1.f-z)*n + z*h1;
        if (s < TT){
            hw_s[wid][lane] = h0;  hw_s[wid][lane+64] = h1;
            __syncthreads();
            float pacc[4][6];
#pragma unroll
            for (int j=0;j<4;j++)
#pragma unroll
                for (int m=0;m<6;m++) pacc[j][m] = 0.f;
            const float4* wr = (const float4*)(wWhP + (size_t)lane*8);
#pragma unroll 4
            for (int kk=0; kk<32; kk++){
                const int k = wid*32 + kk;
                const float4 W0 = wr[k*128], W1 = wr[k*128+1];
#pragma unroll
                for (int j=0;j<4;j++){
                    const float hk = hw_s[j][k];
                    pacc[j][0] += hk*W0.x; pacc[j][1] += hk*W0.y;
                    pacc[j][2] += hk*W0.z; pacc[j][3] += hk*W0.w;
                    pacc[j][4] += hk*W1.x; pacc[j][5] += hk*W1.y;
                }
            }
#pragma unroll
            for (int j=0;j<4;j++)
#pragma unroll
                for (int m=0;m<6;m++) part_s[wid][j][m][lane] = pacc[j][m];
            __syncthreads();
#pragma unroll
            for (int m=0;m<6;m++)
                hg[m] = wb[m] + part_s[0][wid][m][lane] + part_s[1][wid][m][lane]
                              + part_s[2][wid][m][lane] + part_s[3][wid][m][lane];
        }
    }
    hw_s[wid][lane] = h0;  hw_s[wid][lane+64] = h1;
    __syncthreads();

    float acc = wbo[lane];                 // CD == 64 == wave width
    const float* wcol = wWo + lane;
    for (int i=0;i<HD;i++) acc += hw_s[wid][i] * wcol[(size_t)i*CD];
    out[(size_t)node*CD + lane] = acc;
}

extern "C" void kernel_launch(void* const* d_in, const int* in_sizes, int n_in,
                              void* d_out, int out_size, void* d_ws, size_t ws_size,
                              hipStream_t stream)
{
    const float* attr  = (const float*)d_in[0];
    const int*   nbrs  = (const int*)  d_in[1];
    const float* noise = (const float*)d_in[2];
    const float* dWx = (const float*)d_in[3];
    const float* dWh = (const float*)d_in[4];
    const float* dbx = (const float*)d_in[5];
    const float* dbh = (const float*)d_in[6];
    const float* dWo = (const float*)d_in[7];
    const float* dbo = (const float*)d_in[8];
    const float* wWx = (const float*)d_in[9];
    const float* wWh = (const float*)d_in[10];
    const float* wbx = (const float*)d_in[11];
    const float* wbh = (const float*)d_in[12];
    const float* wWo = (const float*)d_in[13];
    const float* wbo = (const float*)d_in[14];
    float* out = (float*)d_out;

    char* ws = (char*)d_ws;
    float* XGfP      = (float*)(ws);                 // 8000*64*8*4 = 16,384,000 B
    float* XGrP      = (float*)(ws + 16384000);      // 8000*64*6*4 = 12,288,000 B
    float* XGwP      = (float*)(ws + 28672000);      // 16,384,000 B
    float* dWhP      = (float*)(ws + 45056000);      // 262,144 B
    float* wWhP      = (float*)(ws + 45318144);      // 262,144 B
    int*   paths     = (int*)  (ws + 45580288);      // 256,000 B
    int*   fail_list = (int*)  (ws + 45836288);      // 32,000 B
    int*   fail_cnt  = (int*)  (ws + 45868288);      // 4 B   (total ~45.9 MB)

    hipMemsetAsync(fail_cnt, 0, sizeof(int), stream);

    xg_kernel<<<NN/8, G3, 0, stream>>>(attr, dWx, dbx, XGfP, XGrP);
    xg_kernel<<<NN/8, G3, 0, stream>>>(attr, wWx, wbx, XGwP, nullptr);
    repack_kernel<<<(HD*64*8)/256, 256, 0, stream>>>(dWh, dWhP);
    repack_kernel<<<(HD*64*8)/256, 256, 0, stream>>>(wWh, wWhP);

    walk_kernel<<<NN/4, 256, 0, stream>>>(nbrs, noise, XGfP, dWhP,
                                          dbh, dWo, dbo,
                                          paths, fail_cnt, fail_list, out);
    fix_kernel<<<2000, 256, 0, stream>>>(nbrs, noise, XGfP, XGrP,
                                         dWhP, dbh, dWo, dbo,
                                         fail_cnt, fail_list, paths, out);
    wgru_kernel<<<NN/4, 256, 0, stream>>>(paths, XGwP, wWhP, wbh, wWo, wbo, out);
}

// Round 13
// 529.139 us; speedup vs baseline: 7.6935x; 1.1351x over previous
//
#include <hip/hip_runtime.h>
#include <math.h>

#define NN 8000   // nodes
#define CD 64     // node feature dim / C_OUT
#define DG 16     // neighbors per node
#define HD 128    // GRU hidden
#define G3 384    // 3*HD
#define TT 4      // walk steps
// Worst-case f32 noisy-score error bound ~1e-3; MARGIN = 4e-3 (proven r8-r12).
#define MARGIN 4e-3f

#if __has_builtin(__builtin_amdgcn_rcpf)
#define RCP(x) __builtin_amdgcn_rcpf(x)
#else
#define RCP(x) (1.f/(x))
#endif

// fast f32 (walk + wgru; error ~1e-6 << MARGIN)
__device__ __forceinline__ float fsig (float x){ return RCP(1.f + __expf(-x)); }
__device__ __forceinline__ float ftanh(float x){ return 1.f - 2.f*RCP(1.f + __expf(2.f*x)); }

// fast f64 exp: range-reduced 13-term Horner, ~3 ulp (validated r9-r12).
__device__ __forceinline__ double fexp64(double x){
    const double LOG2E  = 1.4426950408889634074;
    const double LN2_HI = 6.93147180369123816490e-01;
    const double LN2_LO = 1.90821492927058770002e-10;
    x = fmin(fmax(x, -700.0), 700.0);
    double fn = rint(x * LOG2E);
    double r  = fma(-fn, LN2_HI, x);
    r = fma(-fn, LN2_LO, r);
    double p = 1.6059043836821613e-10;            // 1/13!
    p = fma(p, r, 2.0876756987868099e-09);
    p = fma(p, r, 2.5052108385441719e-08);
    p = fma(p, r, 2.7557319223985893e-07);
    p = fma(p, r, 2.7557319223985888e-06);
    p = fma(p, r, 2.4801587301587302e-05);
    p = fma(p, r, 1.9841269841269841e-04);
    p = fma(p, r, 1.3888888888888889e-03);
    p = fma(p, r, 8.3333333333333332e-03);
    p = fma(p, r, 4.1666666666666664e-02);
    p = fma(p, r, 1.6666666666666666e-01);
    p = fma(p, r, 0.5);
    p = fma(p, r, 1.0);
    p = fma(p, r, 1.0);
    long long bits = __double_as_longlong(p) + ((long long)(int)fn << 52);
    return __longlong_as_double(bits);
}
__device__ __forceinline__ double sig64f (double x){ return 1.0/(1.0 + fexp64(-x)); }
__device__ __forceinline__ double tanh64f(double x){ return 1.0 - 2.0/(fexp64(2.0*x) + 1.0); }

// XG precompute in f64; emit packed-hi [n][64][8] (+ optional residual [n][64][6]).
// Slot q of lane l holds XG[n][64*q + l]; matches hg[m] register order.
__global__ __launch_bounds__(384) void xg_kernel(const float* __restrict__ A,
    const float* __restrict__ W, const float* __restrict__ b,
    float* __restrict__ hiP, float* __restrict__ loP)
{
    __shared__ float a_s[8][64];
    const int g  = threadIdx.x;        // 0..383
    const int l  = g & 63, q = g >> 6;
    const int n0 = blockIdx.x * 8;
    for (int idx = threadIdx.x; idx < 8*64; idx += 384)
        a_s[idx>>6][idx&63] = A[(size_t)n0*64 + idx];
    __syncthreads();
    double acc[8];
    const double bg = (double)b[g];
#pragma unroll
    for (int j=0;j<8;j++) acc[j] = bg;
    for (int c=0;c<64;c++){
        const double w = (double)W[c*G3 + g];
#pragma unroll
        for (int j=0;j<8;j++) acc[j] += (double)a_s[j][c]*w;
    }
#pragma unroll
    for (int j=0;j<8;j++){
        const size_t base = (size_t)(n0+j)*64 + l;
        const float hi = (float)acc[j];
        hiP[base*8 + q] = hi;
        if (q < 2) hiP[base*8 + 6 + q] = 0.f;       // zero pad slots
        if (loP) loP[base*6 + q] = (float)(acc[j] - (double)hi);
    }
}

// Repack Wh [k][384] -> [k][lane][8] (slot m = W[k][64*m+lane], slots 6,7 = 0).
__global__ __launch_bounds__(256) void repack_kernel(const float* __restrict__ W,
                                                     float* __restrict__ P)
{
    const int idx = blockIdx.x*256 + threadIdx.x;   // 0 .. 128*512-1
    const int k = idx >> 9, rem = idx & 511, l = rem >> 3, s = rem & 7;
    P[idx] = (s < 6) ? W[k*G3 + s*64 + l] : 0.f;
}

// Phase 1: pure-f32 walk. 4 waves = 4 nodes per block; block-cooperative
// matvec (4x L2 cut, r11). First margin trip records (node, t0) for the
// fixup kernel; pre-trip selections are certified exact.
__global__ __launch_bounds__(256) void walk_kernel(
    const int*   __restrict__ nbrs,  const float* __restrict__ noise,
    const float* __restrict__ XGfP,  const float* __restrict__ dWhP,
    const float* __restrict__ dbh,   const float* __restrict__ dWo,
    const float* __restrict__ dbo,
    int* __restrict__ paths, int* __restrict__ fail_cnt, int* __restrict__ fail_list,
    float* __restrict__ out)
{
    __shared__ float hf_s[4][HD];            // h of the block's 4 nodes
    __shared__ float part_s[4][4][6][64];    // [writer wave][node][m][lane] 24 KB

    const int wid  = threadIdx.x >> 6;
    const int lane = threadIdx.x & 63;
    const int node = blockIdx.x*4 + wid;

    float h0 = 0.f, h1 = 0.f;
    float dbhf[6], hgf[6];
#pragma unroll
    for (int m=0;m<6;m++){ dbhf[m] = dbh[lane+64*m]; hgf[m] = dbhf[m]; }
    const float wo0f0 = dWo[lane*CD];          // dWo[:,0] lane-local
    const float wo0f1 = dWo[(lane+64)*CD];
    const float dbo0f = dbo[0];

    int  cur = node;
    int  ch0=0, ch1=0, ch2=0, ch3=0;
    bool pushed = false;

    for (int t=0;t<TT;t++){
        if      (t==0) ch0 = cur;
        else if (t==1) ch1 = cur;
        else if (t==2) ch2 = cur;
        else           ch3 = cur;

        // ---- extend prefix (packed row: 2 x b128) ----
        {
            const float4* xr = (const float4*)(XGfP + ((size_t)cur*64 + lane)*8);
            const float4 A = xr[0], B = xr[1];
            float r = fsig (A.x + hgf[0]);
            float z = fsig (A.z + hgf[2]);
            float n = ftanh(B.x + r*hgf[4]);
            h0 = (1.f-z)*n + z*h0;
            r = fsig (A.y + hgf[1]);
            z = fsig (A.w + hgf[3]);
            n = ftanh(B.y + r*hgf[5]);
            h1 = (1.f-z)*n + z*h1;
        }
        hf_s[wid][lane] = h0;  hf_s[wid][lane+64] = h1;
        __syncthreads();                 // (1) all 4 nodes' h visible

        // ---- cooperative matvec: wave wid covers k = 32*wid .. 32*wid+31 ----
        {
            float pacc[4][6];
#pragma unroll
            for (int j=0;j<4;j++)
#pragma unroll
                for (int m=0;m<6;m++) pacc[j][m] = 0.f;
            const float4* wr = (const float4*)(dWhP + (size_t)lane*8);
#pragma unroll 4
            for (int kk=0; kk<32; kk++){
                const int k = wid*32 + kk;
                const float4 W0 = wr[k*128], W1 = wr[k*128+1];
#pragma unroll
                for (int j=0;j<4;j++){
                    const float hk = hf_s[j][k];
                    pacc[j][0] += hk*W0.x; pacc[j][1] += hk*W0.y;
                    pacc[j][2] += hk*W0.z; pacc[j][3] += hk*W0.w;
                    pacc[j][4] += hk*W1.x; pacc[j][5] += hk*W1.y;
                }
            }
#pragma unroll
            for (int j=0;j<4;j++)
#pragma unroll
                for (int m=0;m<6;m++) part_s[wid][j][m][lane] = pacc[j][m];
        }
        __syncthreads();                 // (2) partials visible

#pragma unroll
        for (int m=0;m<6;m++)
            hgf[m] = dbhf[m] + part_s[0][wid][m][lane] + part_s[1][wid][m][lane]
                             + part_s[2][wid][m][lane] + part_s[3][wid][m][lane];

        // ---- 16 candidates, 4 groups of 4 with prefetch (per-wave, no barriers) ----
        int   nbrv = (lane < DG) ? nbrs[(size_t)cur*DG + lane] : 0;
        float nz   = (lane < DG) ? noise[((size_t)t*NN + node)*DG + lane] : 0.f;
        float lf = -3.0e38f;
#pragma unroll
        for (int g=0; g<4; g++){
            float4 CA[4], CB[4];
#pragma unroll
            for (int j=0;j<4;j++){
                const int nd = __shfl(nbrv, g*4+j);
                const float4* cr = (const float4*)(XGfP + ((size_t)nd*64 + lane)*8);
                CA[j] = cr[0];  CB[j] = cr[1];
            }
            float part[4];
#pragma unroll
            for (int j=0;j<4;j++){
                float r = fsig (CA[j].x + hgf[0]);
                float z = fsig (CA[j].z + hgf[2]);
                float n = ftanh(CB[j].x + r*hgf[4]);
                part[j]  = ((1.f-z)*n + z*h0) * wo0f0;
                r = fsig (CA[j].y + hgf[1]);
                z = fsig (CA[j].w + hgf[3]);
                n = ftanh(CB[j].y + r*hgf[5]);
                part[j] += ((1.f-z)*n + z*h1) * wo0f1;
            }
#pragma unroll
            for (int off=32; off>0; off>>=1){
#pragma unroll
                for (int j=0;j<4;j++) part[j] += __shfl_xor(part[j], off);
            }
#pragma unroll
            for (int j=0;j<4;j++) if (lane == g*4+j) lf = part[j] + dbo0f;
        }

        // ---- softmax + noisy argmax + top-2 margin ----
        float v  = (lane < DG) ? lf : -3.0e38f;
        float mx = v;
#pragma unroll
        for (int off=32; off>0; off>>=1) mx = fmaxf(mx, __shfl_xor(mx, off));
        float e = (lane < DG) ? __expf(v - mx) : 0.f;
        float s = e;
#pragma unroll
        for (int off=32; off>0; off>>=1) s += __shfl_xor(s, off);
        const float normf = mx + __logf(s);

        float noisyf = (lane < DG) ? __expf(v - normf) + 0.01f*nz : -3.0e38f;
        int   idx = lane;
        float bv  = noisyf;
#pragma unroll
        for (int off=32; off>0; off>>=1){
            float ov = __shfl_xor(bv, off);
            int   oi = __shfl_xor(idx, off);
            if (ov > bv || (ov == bv && oi < idx)){ bv = ov; idx = oi; }
        }
        float sv = (lane == idx || lane >= DG) ? -3.0e38f : noisyf;
#pragma unroll
        for (int off=32; off>0; off>>=1) sv = fmaxf(sv, __shfl_xor(sv, off));

        const bool trip = (bv - sv) < MARGIN;   // wave-uniform
        if (trip && !pushed){
            if (lane == 0){
                const int slot = atomicAdd(fail_cnt, 1);
                if (slot < NN) fail_list[slot] = node | (t << 16);  // first trip step
            }
            pushed = true;
        }

        const float lpf = __shfl(v, idx) - normf;
        if (lane == 0) out[NN*CD + node*TT + t] = lpf;
        cur = __shfl(nbrv, idx);
    }

    if (lane == 0){
        int* p = paths + (size_t)node*8;
        p[0]=ch0; p[1]=ch1; p[2]=ch2; p[3]=ch3; p[4]=cur;
    }
}

// Phase 2: exact-f64 redo. r13: BLOCK-COOPERATIVE f64 matvec (4 waves cover
// k-quarters for all 4 nodes; 2 barriers/step) cuts the serial k-chain
// 128->32 — fix was per-node LATENCY-bound (r12: 1 node/wave, 300us ~= one
// node's replay latency, matvec-dominated). Scoring/gathers stay per-wave
// and barrier-free (r9 lesson). All waves run exactly TT matvec steps, so
// barriers are uniform; idle waves ride along with node 0's prefix.
__global__ __launch_bounds__(256) void fix_kernel(
    const int*   __restrict__ nbrs,  const float* __restrict__ noise,
    const float* __restrict__ XGfP,  const float* __restrict__ XGrP,
    const float* __restrict__ dWhP,  const float* __restrict__ dbh,
    const float* __restrict__ dWo,   const float* __restrict__ dbo,
    const int* __restrict__ fail_cnt, const int* __restrict__ fail_list,
    int* __restrict__ paths, float* __restrict__ out)
{
    __shared__ double h_s[4][HD];            // 4 KB
    __shared__ double part_s[4][4][6][64];   // 48 KB: [writer][node][m][lane]

    const int wid  = threadIdx.x >> 6;
    const int lane = threadIdx.x & 63;
    const int count = min(fail_cnt[0], NN);
    if (blockIdx.x*4 >= count) return;       // whole-block early exit (uniform)

    const int  ii     = blockIdx.x*4 + wid;
    const bool active = (ii < count);
    const int  entry  = active ? fail_list[ii] : fail_list[0];
    const int  node   = entry & 0xFFFF;
    const int  t0     = active ? (entry >> 16) : TT;   // idle: prefix-only
    const int* pw     = paths + (size_t)node*8;

    double db64[6];
#pragma unroll
    for (int m=0;m<6;m++) db64[m] = (double)dbh[lane+64*m];
    const double wo0d0 = (double)dWo[lane*CD];
    const double wo0d1 = (double)dWo[(lane+64)*CD];
    const double dbo0d = (double)dbo[0];

    double H0 = 0.0, H1 = 0.0;
    double g64[6];
#pragma unroll
    for (int m=0;m<6;m++) g64[m] = db64[m];
    int cur = node;
    int c0=0,c1=0,c2=0,c3=0;

    for (int t=0;t<TT;t++){
        if      (t==0) c0 = cur;
        else if (t==1) c1 = cur;
        else if (t==2) c2 = cur;
        else           c3 = cur;

        // ---- extend (f64 = hi + residual) ----
        {
            const size_t base = (size_t)cur*64 + lane;
            const float* hi = XGfP + base*8;
            const float* lo = XGrP + base*6;
            double r = sig64f (((double)hi[0]+(double)lo[0]) + g64[0]);
            double z = sig64f (((double)hi[2]+(double)lo[2]) + g64[2]);
            double n = tanh64f(((double)hi[4]+(double)lo[4]) + r*g64[4]);
            H0 = (1.0-z)*n + z*H0;
            r = sig64f (((double)hi[1]+(double)lo[1]) + g64[1]);
            z = sig64f (((double)hi[3]+(double)lo[3]) + g64[3]);
            n = tanh64f(((double)hi[5]+(double)lo[5]) + r*g64[5]);
            H1 = (1.0-z)*n + z*H1;
        }
        h_s[wid][lane] = H0;  h_s[wid][lane+64] = H1;
        __syncthreads();                 // (1) all 4 nodes' h visible

        // ---- cooperative f64 matvec: wave wid covers k = 32*wid..+31 ----
        {
            double pacc[4][6];
#pragma unroll
            for (int j=0;j<4;j++)
#pragma unroll
                for (int m=0;m<6;m++) pacc[j][m] = 0.0;
            const float4* wr = (const float4*)(dWhP + (size_t)lane*8);
#pragma unroll 4
            for (int kk=0; kk<32; kk++){
                const int k = wid*32 + kk;
                const float4 W0 = wr[k*128], W1 = wr[k*128+1];
#pragma unroll
                for (int j=0;j<4;j++){
                    const double hk = h_s[j][k];
                    pacc[j][0] += hk*(double)W0.x; pacc[j][1] += hk*(double)W0.y;
                    pacc[j][2] += hk*(double)W0.z; pacc[j][3] += hk*(double)W0.w;
                    pacc[j][4] += hk*(double)W1.x; pacc[j][5] += hk*(double)W1.y;
                }
            }
#pragma unroll
            for (int j=0;j<4;j++)
#pragma unroll
                for (int m=0;m<6;m++) part_s[wid][j][m][lane] = pacc[j][m];
        }
        __syncthreads();                 // (2) partials visible

#pragma unroll
        for (int m=0;m<6;m++)
            g64[m] = db64[m] + part_s[0][wid][m][lane] + part_s[1][wid][m][lane]
                             + part_s[2][wid][m][lane] + part_s[3][wid][m][lane];

        // ---- certified prefix: skip scoring, follow recorded path ----
        if (t < t0){
            cur = pw[t+1];
            continue;                    // no barriers below — safe divergence
        }

        // ---- 16 candidates f64, 4 groups of 4 with prefetch ----
        int   nbrv = (lane < DG) ? nbrs[(size_t)cur*DG + lane] : 0;
        float nz   = (lane < DG) ? noise[((size_t)t*NN + node)*DG + lane] : 0.f;
        double lv = -1e300;
#pragma unroll
        for (int g=0; g<4; g++){
            float ch[4][6], cl[4][6];
#pragma unroll
            for (int j=0;j<4;j++){
                const int nd = __shfl(nbrv, g*4+j);
                const size_t base = (size_t)nd*64 + lane;
                const float* hi = XGfP + base*8;
                const float* lo = XGrP + base*6;
#pragma unroll
                for (int q=0;q<6;q++){ ch[j][q]=hi[q]; cl[j][q]=lo[q]; }
            }
#pragma unroll
            for (int j=0;j<4;j++){
                double r = sig64f (((double)ch[j][0]+(double)cl[j][0]) + g64[0]);
                double z = sig64f (((double)ch[j][2]+(double)cl[j][2]) + g64[2]);
                double n = tanh64f(((double)ch[j][4]+(double)cl[j][4]) + r*g64[4]);
                double part = ((1.0-z)*n + z*H0) * wo0d0;
                r = sig64f (((double)ch[j][1]+(double)cl[j][1]) + g64[1]);
                z = sig64f (((double)ch[j][3]+(double)cl[j][3]) + g64[3]);
                n = tanh64f(((double)ch[j][5]+(double)cl[j][5]) + r*g64[5]);
                part += ((1.0-z)*n + z*H1) * wo0d1;
#pragma unroll
                for (int off=32; off>0; off>>=1) part += __shfl_xor(part, off);
                if (lane == g*4+j) lv = part + dbo0d;
            }
        }

        // ---- softmax + noisy argmax (identical numerics to r9-r12) ----
        double dv = (lane < DG) ? lv : -1e300;
        double dmx = dv;
#pragma unroll
        for (int off=32; off>0; off>>=1) dmx = fmax(dmx, __shfl_xor(dmx, off));
        double de = (lane < DG) ? fexp64(dv - dmx) : 0.0;
        double ds = de;
#pragma unroll
        for (int off=32; off>0; off>>=1) ds += __shfl_xor(ds, off);
        const double dnorm = dmx + log(ds);
        double dnoisy = (lane < DG) ? fexp64(dv - dnorm) + 0.01*(double)nz : -1e300;
        int di = lane;
#pragma unroll
        for (int off=32; off>0; off>>=1){
            double ov = __shfl_xor(dnoisy, off);
            int    oi = __shfl_xor(di, off);
            if (ov > dnoisy || (ov == dnoisy && oi < di)){ dnoisy = ov; di = oi; }
        }
        const double lpfix = __shfl(dv, di) - dnorm;
        if (active && lane == 0) out[NN*CD + node*TT + t] = (float)lpfix;
        cur = __shfl(nbrv, di);
    }

    if (active && lane == 0){
        int* p = paths + (size_t)node*8;
        p[0]=c0; p[1]=c1; p[2]=c2; p[3]=c3; p[4]=cur;
    }
}

// w-GRU over the recorded 5-node walk; block-cooperative matvec (r11).
__global__ __launch_bounds__(256) void wgru_kernel(
    const int*   __restrict__ paths, const float* __restrict__ XGwP,
    const float* __restrict__ wWhP,  const float* __restrict__ wbh,
    const float* __restrict__ wWo,   const float* __restrict__ wbo,
    float* __restrict__ out)
{
    __shared__ float hw_s[4][HD];
    __shared__ float part_s[4][4][6][64];
    const int wid  = threadIdx.x >> 6;
    const int lane = threadIdx.x & 63;
    const int node = blockIdx.x*4 + wid;

    float h0 = 0.f, h1 = 0.f;
    float wb[6], hg[6];
#pragma unroll
    for (int m=0;m<6;m++){ wb[m] = wbh[lane+64*m]; hg[m] = wb[m]; }
    const int* p = paths + (size_t)node*8;

#pragma unroll
    for (int s=0; s<=TT; s++){
        const int c = p[s];
        const float4* xr = (const float4*)(XGwP + ((size_t)c*64 + lane)*8);
        const float4 A = xr[0], B = xr[1];
        float r = fsig (A.x + hg[0]);
        float z = fsig (A.z + hg[2]);
        float n = ftanh(B.x + r*hg[4]);
        h0 = (1.f-z)*n + z*h0;
        r = fsig (A.y + hg[1]);
        z = fsig (A.w + hg[3]);
        n = ftanh(B.y + r*hg[5]);
        h1 = (1.f-z)*n + z*h1;
        if (s < TT){
            hw_s[wid][lane] = h0;  hw_s[wid][lane+64] = h1;
            __syncthreads();
            float pacc[4][6];
#pragma unroll
            for (int j=0;j<4;j++)
#pragma unroll
                for (int m=0;m<6;m++) pacc[j][m] = 0.f;
            const float4* wr = (const float4*)(wWhP + (size_t)lane*8);
#pragma unroll 4
            for (int kk=0; kk<32; kk++){
                const int k = wid*32 + kk;
                const float4 W0 = wr[k*128], W1 = wr[k*128+1];
#pragma unroll
                for (int j=0;j<4;j++){
                    const float hk = hw_s[j][k];
                    pacc[j][0] += hk*W0.x; pacc[j][1] += hk*W0.y;
                    pacc[j][2] += hk*W0.z; pacc[j][3] += hk*W0.w;
                    pacc[j][4] += hk*W1.x; pacc[j][5] += hk*W1.y;
                }
            }
#pragma unroll
            for (int j=0;j<4;j++)
#pragma unroll
                for (int m=0;m<6;m++) part_s[wid][j][m][lane] = pacc[j][m];
            __syncthreads();
#pragma unroll
            for (int m=0;m<6;m++)
                hg[m] = wb[m] + part_s[0][wid][m][lane] + part_s[1][wid][m][lane]
                              + part_s[2][wid][m][lane] + part_s[3][wid][m][lane];
        }
    }
    hw_s[wid][lane] = h0;  hw_s[wid][lane+64] = h1;
    __syncthreads();

    float acc = wbo[lane];                 // CD == 64 == wave width
    const float* wcol = wWo + lane;
    for (int i=0;i<HD;i++) acc += hw_s[wid][i] * wcol[(size_t)i*CD];
    out[(size_t)node*CD + lane] = acc;
}

extern "C" void kernel_launch(void* const* d_in, const int* in_sizes, int n_in,
                              void* d_out, int out_size, void* d_ws, size_t ws_size,
                              hipStream_t stream)
{
    const float* attr  = (const float*)d_in[0];
    const int*   nbrs  = (const int*)  d_in[1];
    const float* noise = (const float*)d_in[2];
    const float* dWx = (const float*)d_in[3];
    const float* dWh = (const float*)d_in[4];
    const float* dbx = (const float*)d_in[5];
    const float* dbh = (const float*)d_in[6];
    const float* dWo = (const float*)d_in[7];
    const float* dbo = (const float*)d_in[8];
    const float* wWx = (const float*)d_in[9];
    const float* wWh = (const float*)d_in[10];
    const float* wbx = (const float*)d_in[11];
    const float* wbh = (const float*)d_in[12];
    const float* wWo = (const float*)d_in[13];
    const float* wbo = (const float*)d_in[14];
    float* out = (float*)d_out;

    char* ws = (char*)d_ws;
    float* XGfP      = (float*)(ws);                 // 8000*64*8*4 = 16,384,000 B
    float* XGrP      = (float*)(ws + 16384000);      // 8000*64*6*4 = 12,288,000 B
    float* XGwP      = (float*)(ws + 28672000);      // 16,384,000 B
    float* dWhP      = (float*)(ws + 45056000);      // 262,144 B
    float* wWhP      = (float*)(ws + 45318144);      // 262,144 B
    int*   paths     = (int*)  (ws + 45580288);      // 256,000 B
    int*   fail_list = (int*)  (ws + 45836288);      // 32,000 B
    int*   fail_cnt  = (int*)  (ws + 45868288);      // 4 B   (total ~45.9 MB)

    hipMemsetAsync(fail_cnt, 0, sizeof(int), stream);

    xg_kernel<<<NN/8, G3, 0, stream>>>(attr, dWx, dbx, XGfP, XGrP);
    xg_kernel<<<NN/8, G3, 0, stream>>>(attr, wWx, wbx, XGwP, nullptr);
    repack_kernel<<<(HD*64*8)/256, 256, 0, stream>>>(dWh, dWhP);
    repack_kernel<<<(HD*64*8)/256, 256, 0, stream>>>(wWh, wWhP);

    walk_kernel<<<NN/4, 256, 0, stream>>>(nbrs, noise, XGfP, dWhP,
                                          dbh, dWo, dbo,
                                          paths, fail_cnt, fail_list, out);
    fix_kernel<<<2000, 256, 0, stream>>>(nbrs, noise, XGfP, XGrP,
                                         dWhP, dbh, dWo, dbo,
                                         fail_cnt, fail_list, paths, out);
    wgru_kernel<<<NN/4, 256, 0, stream>>>(paths, XGwP, wWhP, wbh, wWo, wbo, out);
}